// Round 1
// baseline (1414.557 us; speedup 1.0000x reference)
//
#include <hip/hip_runtime.h>
#include <cstdint>
#include <cstddef>

#define B_   2
#define S_   2048
#define HID_ 4096
#define H_   32
#define KV_  8
#define D_   128
#define M_   (B_*S_)      // 4096 tokens
#define QSTR 6144         // QKV combined row stride (H*D + 2*KV*D)

typedef __attribute__((ext_vector_type(8))) short bf16x8;
typedef __attribute__((ext_vector_type(4))) float f32x4;
typedef unsigned short u16;
typedef unsigned int   u32;

// softmax scale folded into exp2: SCALE * log2(e)
#define KSC (0.08838834764831845f * 1.4426950408889634f)

__device__ __forceinline__ float bf2f(u16 v){ u32 u = ((u32)v) << 16; return __builtin_bit_cast(float, u); }
__device__ __forceinline__ u16 f2bf(float f){
  u32 u = __builtin_bit_cast(u32, f);
  u32 r = u + 0x7fffu + ((u >> 16) & 1u);   // RNE
  return (u16)(r >> 16);
}

__device__ __forceinline__ void gload_lds16(const void* g, void* lds){
  __builtin_amdgcn_global_load_lds(
      (const __attribute__((address_space(1))) void*)g,
      (__attribute__((address_space(3))) void*)lds, 16, 0, 0);
}

// ---------------- cast fp32 -> bf16 (vectorized) ----------------
__global__ void cast_f32_bf16(const float* __restrict__ in, u16* __restrict__ out, int n){
  int i = (blockIdx.x * blockDim.x + threadIdx.x) * 4;
  if (i >= n) return;
  float4 v = *(const float4*)(in + i);
  ushort4 o;
  o.x = f2bf(v.x); o.y = f2bf(v.y); o.z = f2bf(v.z); o.w = f2bf(v.w);
  *(ushort4*)(out + i) = o;
}

// ---------------- transpose-cast: W[Kd][Nd] fp32 -> WT[Nd][Kd] bf16 ----------------
__global__ __launch_bounds__(256) void tcast(const float* __restrict__ W, u16* __restrict__ WT,
                                             int Kd, int Nd){
  __shared__ __align__(16) u16 t[64][65];     // t[n][k]
  int k0 = blockIdx.x * 64, n0 = blockIdx.y * 64;
  int lx = threadIdx.x & 15, ly = threadIdx.x >> 4;
  #pragma unroll
  for (int rr = 0; rr < 4; ++rr){
    int r = rr * 16 + ly;                     // k-row in tile
    float4 v = *(const float4*)(W + (size_t)(k0 + r) * Nd + n0 + lx * 4);
    t[lx*4+0][r] = f2bf(v.x);
    t[lx*4+1][r] = f2bf(v.y);
    t[lx*4+2][r] = f2bf(v.z);
    t[lx*4+3][r] = f2bf(v.w);
  }
  __syncthreads();
  #pragma unroll
  for (int rr = 0; rr < 4; ++rr){
    int r = rr * 16 + ly;                     // n-row in tile
    ushort4 o;
    o.x = t[r][lx*4+0]; o.y = t[r][lx*4+1]; o.z = t[r][lx*4+2]; o.w = t[r][lx*4+3];
    *(ushort4*)(WT + (size_t)(n0 + r) * Kd + k0 + lx * 4) = o;
  }
}

// ---------------- GEMM: C[M,N] = A[M,Kd](bf16) @ Bt[N,Kd]^T(bf16), m97 structure ----------------
template<bool OUTF32>
__global__ __launch_bounds__(256) void gemm_bt(const u16* __restrict__ A, const u16* __restrict__ Bt,
                                               void* __restrict__ C, int Nn, int Kd){
  __shared__ __align__(16) u16 As[128 * 32];
  __shared__ __align__(16) u16 Bs[128 * 32];
  const int tid = threadIdx.x;
  const int l = tid & 63, w = tid >> 6;
  const int wm = w >> 1, wn = w & 1;
  const int lr = l & 15, lk = l >> 4;
  const size_t arow0 = (size_t)blockIdx.x * 128;
  const size_t brow0 = (size_t)blockIdx.y * 128;
  const u16* Ag = A + arow0 * Kd;
  const u16* Bg = Bt + brow0 * Kd;

  f32x4 acc[4][4];
  #pragma unroll
  for (int i = 0; i < 4; ++i)
    #pragma unroll
    for (int j = 0; j < 4; ++j){ acc[i][j][0]=0.f; acc[i][j][1]=0.f; acc[i][j][2]=0.f; acc[i][j][3]=0.f; }

  const int nk = Kd >> 5;
  for (int kt = 0; kt < nk; ++kt){
    __syncthreads();
    #pragma unroll
    for (int c = 0; c < 2; ++c){
      int qbase = (c * 4 + w) * 64;
      int q = qbase + l;
      int r = q >> 2, kc = q & 3;
      gload_lds16(Ag + (size_t)r * Kd + kt * 32 + kc * 8, &As[qbase * 8]);
      gload_lds16(Bg + (size_t)r * Kd + kt * 32 + kc * 8, &Bs[qbase * 8]);
    }
    __syncthreads();   // compiler drains vmcnt before barrier

    bf16x8 af[4], bfr[4];
    #pragma unroll
    for (int mf = 0; mf < 4; ++mf)
      af[mf] = *(const bf16x8*)&As[(wm*64 + mf*16 + lr) * 32 + lk * 8];
    #pragma unroll
    for (int nf = 0; nf < 4; ++nf)
      bfr[nf] = *(const bf16x8*)&Bs[(wn*64 + nf*16 + lr) * 32 + lk * 8];
    #pragma unroll
    for (int mf = 0; mf < 4; ++mf)
      #pragma unroll
      for (int nf = 0; nf < 4; ++nf)
        acc[mf][nf] = __builtin_amdgcn_mfma_f32_16x16x32_bf16(af[mf], bfr[nf], acc[mf][nf], 0, 0, 0);
  }

  // epilogue: C row = (lane>>4)*4 + j, col = lane&15  [m89-verified layout]
  #pragma unroll
  for (int mf = 0; mf < 4; ++mf)
    #pragma unroll
    for (int nf = 0; nf < 4; ++nf)
      #pragma unroll
      for (int j = 0; j < 4; ++j){
        size_t gr = arow0 + wm*64 + mf*16 + lk*4 + j;
        size_t gc = brow0 + wn*64 + nf*16 + lr;
        float v = acc[mf][nf][j];
        if (OUTF32) ((float*)C)[gr * Nn + gc] = v;
        else        ((u16*)C)[gr * Nn + gc] = f2bf(v);
      }
}

// ---------------- RoPE in-place on bf16 [M_][stride] rows, nh = 1<<hshift heads ----------------
__global__ void rope_k(u16* __restrict__ X, const int* __restrict__ pos, int hshift, int stride){
  int idx = blockIdx.x * 256 + threadIdx.x;
  int i = idx & 63;
  int h = (idx >> 6) & ((1 << hshift) - 1);
  int t = idx >> (6 + hshift);
  u16* p0 = X + (size_t)t * stride + h * D_ + i;
  float x1 = bf2f(p0[0]), x2 = bf2f(p0[64]);
  float fpos = (float)pos[t];
  float invf = exp2f(-(float)(2 * i) * (13.287712379549449f / 128.0f)); // theta^(-2i/D)
  float f = fpos * invf;
  float sv = __sinf(f), cv = __cosf(f);
  p0[0]  = f2bf(x1 * cv - x2 * sv);
  p0[64] = f2bf(x2 * cv + x1 * sv);
}

// ---------------- flash attention: 4 waves x 16 q-rows, KBLK=32, causal ----------------
__global__ __launch_bounds__(256) void attn_k(const u16* __restrict__ QKV, u16* __restrict__ ctx){
  __shared__ __align__(16) u16 Vt[128][40];       // Vt[d][k], padded stride
  __shared__ __align__(16) u16 Ps[4][16][40];     // per-wave P tile
  const int tid = threadIdx.x, l = tid & 63, w = tid >> 6;
  const int lr = l & 15, lk = l >> 4;
  const int bh = blockIdx.y, b = bh >> 5, h = bh & 31, kvh = h >> 2;
  const int q0b = blockIdx.x * 64;
  const int q0 = q0b + w * 16;
  const u16* Qp = QKV + (size_t)b * S_ * QSTR + (size_t)h * D_;
  const u16* Kp = QKV + (size_t)b * S_ * QSTR + 4096 + (size_t)kvh * D_;
  const u16* Vp = QKV + (size_t)b * S_ * QSTR + 5120 + (size_t)kvh * D_;

  bf16x8 qf[4];
  #pragma unroll
  for (int dc = 0; dc < 4; ++dc)
    qf[dc] = *(const bf16x8*)(Qp + (size_t)(q0 + lr) * QSTR + dc * 32 + lk * 8);

  f32x4 acc[8];
  #pragma unroll
  for (int i = 0; i < 8; ++i){ acc[i][0]=0.f; acc[i][1]=0.f; acc[i][2]=0.f; acc[i][3]=0.f; }
  float mrow[4] = {-3e38f, -3e38f, -3e38f, -3e38f};
  float lsum[4] = {0.f, 0.f, 0.f, 0.f};

  const int ntiles = (q0b >> 5) + 2;
  for (int kt = 0; kt < ntiles; ++kt){
    const int kbase = kt * 32;
    __syncthreads();
    // stage V-tile transposed into LDS (shared by all 4 waves)
    #pragma unroll
    for (int c = 0; c < 2; ++c){
      int ci = c * 256 + tid;
      int row = ci >> 4, dch = ci & 15;
      bf16x8 vv = *(const bf16x8*)(Vp + (size_t)(kbase + row) * QSTR + dch * 8);
      #pragma unroll
      for (int jj = 0; jj < 8; ++jj) Vt[dch*8 + jj][row] = (u16)vv[jj];
    }
    __syncthreads();

    // S = Q K^T  (16 q-rows x 32 k-cols per wave)
    f32x4 sf[2];
    #pragma unroll
    for (int nf = 0; nf < 2; ++nf){ sf[nf][0]=0.f; sf[nf][1]=0.f; sf[nf][2]=0.f; sf[nf][3]=0.f; }
    #pragma unroll
    for (int nf = 0; nf < 2; ++nf)
      #pragma unroll
      for (int dc = 0; dc < 4; ++dc){
        bf16x8 kf = *(const bf16x8*)(Kp + (size_t)(kbase + nf*16 + lr) * QSTR + dc * 32 + lk * 8);
        sf[nf] = __builtin_amdgcn_mfma_f32_16x16x32_bf16(qf[dc], kf, sf[nf], 0, 0, 0);
      }

    // causal mask + online softmax (wave-parallel, 16-lane groups)
    float pr[2][4], tmax[4], psum[4];
    #pragma unroll
    for (int j = 0; j < 4; ++j){
      int qr = q0 + lk * 4 + j;
      #pragma unroll
      for (int nf = 0; nf < 2; ++nf){
        int kc = kbase + nf * 16 + lr;
        if (kc > qr) sf[nf][j] = -1e30f;
      }
      tmax[j] = fmaxf(sf[0][j], sf[1][j]);
    }
    #pragma unroll
    for (int j = 0; j < 4; ++j)
      #pragma unroll
      for (int o = 1; o < 16; o <<= 1) tmax[j] = fmaxf(tmax[j], __shfl_xor(tmax[j], o));
    #pragma unroll
    for (int j = 0; j < 4; ++j){
      float mn = fmaxf(mrow[j], tmax[j]);
      float r = exp2f((mrow[j] - mn) * KSC);
      mrow[j] = mn;
      lsum[j] *= r;
      #pragma unroll
      for (int i = 0; i < 8; ++i) acc[i][j] *= r;
      float p0 = exp2f((sf[0][j] - mn) * KSC);
      float p1 = exp2f((sf[1][j] - mn) * KSC);
      pr[0][j] = p0; pr[1][j] = p1;
      psum[j] = p0 + p1;
    }
    #pragma unroll
    for (int j = 0; j < 4; ++j){
      #pragma unroll
      for (int o = 1; o < 16; o <<= 1) psum[j] += __shfl_xor(psum[j], o);
      lsum[j] += psum[j];
    }

    // P (C-layout) -> LDS -> A-layout fragment
    #pragma unroll
    for (int nf = 0; nf < 2; ++nf)
      #pragma unroll
      for (int j = 0; j < 4; ++j)
        Ps[w][lk*4 + j][nf*16 + lr] = f2bf(pr[nf][j]);
    bf16x8 pa = *(const bf16x8*)&Ps[w][lr][lk * 8];

    // PV: acc[16 q][128 d] += P @ V
    #pragma unroll
    for (int nf2 = 0; nf2 < 8; ++nf2){
      bf16x8 vf = *(const bf16x8*)&Vt[nf2*16 + lr][lk * 8];
      acc[nf2] = __builtin_amdgcn_mfma_f32_16x16x32_bf16(pa, vf, acc[nf2], 0, 0, 0);
    }
  }

  // epilogue: ctx[t][h*D + d] bf16, token-major
  float inv[4];
  #pragma unroll
  for (int j = 0; j < 4; ++j) inv[j] = 1.0f / lsum[j];
  #pragma unroll
  for (int nf2 = 0; nf2 < 8; ++nf2)
    #pragma unroll
    for (int j = 0; j < 4; ++j){
      size_t t = (size_t)(b * S_ + q0 + lk*4 + j);
      ctx[t * HID_ + h * D_ + nf2*16 + lr] = f2bf(acc[nf2][j] * inv[j]);
    }
}

extern "C" void kernel_launch(void* const* d_in, const int* in_sizes, int n_in,
                              void* d_out, int out_size, void* d_ws, size_t ws_size,
                              hipStream_t stream) {
  const float* x  = (const float*)d_in[0];
  // d_in[1] = attention_mask (pure causal; applied analytically)
  const int*   pos = (const int*)d_in[2];
  const float* Wq = (const float*)d_in[3];
  const float* Wk = (const float*)d_in[4];
  const float* Wv = (const float*)d_in[5];
  const float* Wo = (const float*)d_in[6];

  char* ws = (char*)d_ws;
  u16* xb   = (u16*)(ws);                               // 32MB; reused as ctx after QKV
  u16* WT   = (u16*)(ws + ((size_t)32 << 20));          // 48MB: [6144][4096] = Wq^T|Wk^T|Wv^T
  u16* WoT  = (u16*)(ws + ((size_t)80 << 20));          // 32MB
  u16* QKVb = (u16*)(ws + ((size_t)112 << 20));         // 48MB: [4096][6144]

  // 1. cast x -> bf16
  cast_f32_bf16<<<16384, 256, 0, stream>>>(x, xb, HID_ * M_);
  // 2. transpose-cast weights
  tcast<<<dim3(64, 64), 256, 0, stream>>>(Wq, WT, 4096, 4096);
  tcast<<<dim3(64, 16), 256, 0, stream>>>(Wk, WT + (size_t)4096 * 4096, 4096, 1024);
  tcast<<<dim3(64, 16), 256, 0, stream>>>(Wv, WT + (size_t)5120 * 4096, 4096, 1024);
  tcast<<<dim3(64, 64), 256, 0, stream>>>(Wo, WoT, 4096, 4096);
  // 3. fused QKV projection: [4096][6144] bf16
  gemm_bt<false><<<dim3(32, 48), 256, 0, stream>>>(xb, WT, QKVb, 6144, 4096);
  // 4. RoPE in-place on Q (32 heads) and K (8 heads)
  rope_k<<<32768, 256, 0, stream>>>(QKVb,        pos, 5, QSTR);
  rope_k<<<8192,  256, 0, stream>>>(QKVb + 4096, pos, 3, QSTR);
  // 5. causal flash attention -> ctx (reuses xb)
  attn_k<<<dim3(32, 64), 256, 0, stream>>>(QKVb, xb);
  // 6. output projection -> fp32 d_out
  gemm_bt<true><<<dim3(32, 32), 256, 0, stream>>>(xb, WoT, d_out, 4096, 4096);
}

// Round 2
// 664.578 us; speedup vs baseline: 2.1285x; 2.1285x over previous
//
#include <hip/hip_runtime.h>
#include <cstdint>
#include <cstddef>

#define B_   2
#define S_   2048
#define HID_ 4096
#define H_   32
#define KV_  8
#define D_   128
#define M_   (B_*S_)      // 4096 tokens
#define QSTR 6144         // QKV combined row stride (H*D + 2*KV*D)

typedef __attribute__((ext_vector_type(8))) short bf16x8;
typedef __attribute__((ext_vector_type(4))) float f32x4;
typedef __attribute__((ext_vector_type(16))) float f32x16;
typedef __attribute__((ext_vector_type(4))) unsigned int u32x4;
typedef unsigned short u16;
typedef unsigned int   u32;

// softmax scale folded into exp2: SCALE * log2(e)
#define KSC (0.08838834764831845f * 1.4426950408889634f)

__device__ __forceinline__ float bf2f(u16 v){ u32 u = ((u32)v) << 16; return __builtin_bit_cast(float, u); }
__device__ __forceinline__ u16 f2bf(float f){
  u32 u = __builtin_bit_cast(u32, f);
  u32 r = u + 0x7fffu + ((u >> 16) & 1u);   // RNE
  return (u16)(r >> 16);
}

__device__ __forceinline__ void gload_lds16(const void* g, void* lds){
  __builtin_amdgcn_global_load_lds(
      (const __attribute__((address_space(1))) void*)g,
      (__attribute__((address_space(3))) void*)lds, 16, 0, 0);
}

// ---------------- cast fp32 -> bf16 (vectorized) ----------------
__global__ void cast_f32_bf16(const float* __restrict__ in, u16* __restrict__ out, int n){
  int i = (blockIdx.x * blockDim.x + threadIdx.x) * 4;
  if (i >= n) return;
  float4 v = *(const float4*)(in + i);
  ushort4 o;
  o.x = f2bf(v.x); o.y = f2bf(v.y); o.z = f2bf(v.z); o.w = f2bf(v.w);
  *(ushort4*)(out + i) = o;
}

// ---------------- transpose-cast: W[Kd][Nd] fp32 -> WT[Nd][Kd] bf16 ----------------
__global__ __launch_bounds__(256) void tcast(const float* __restrict__ W, u16* __restrict__ WT,
                                             int Kd, int Nd){
  __shared__ __align__(16) u16 t[64][65];     // t[n][k]
  int k0 = blockIdx.x * 64, n0 = blockIdx.y * 64;
  int lx = threadIdx.x & 15, ly = threadIdx.x >> 4;
  #pragma unroll
  for (int rr = 0; rr < 4; ++rr){
    int r = rr * 16 + ly;                     // k-row in tile
    float4 v = *(const float4*)(W + (size_t)(k0 + r) * Nd + n0 + lx * 4);
    t[lx*4+0][r] = f2bf(v.x);
    t[lx*4+1][r] = f2bf(v.y);
    t[lx*4+2][r] = f2bf(v.z);
    t[lx*4+3][r] = f2bf(v.w);
  }
  __syncthreads();
  #pragma unroll
  for (int rr = 0; rr < 4; ++rr){
    int r = rr * 16 + ly;                     // n-row in tile
    ushort4 o;
    o.x = t[r][lx*4+0]; o.y = t[r][lx*4+1]; o.z = t[r][lx*4+2]; o.w = t[r][lx*4+3];
    *(ushort4*)(WT + (size_t)(n0 + r) * Kd + k0 + lx * 4) = o;
  }
}

// ---------------- transpose V (bf16): QKV[t][5120 + vd] -> Vt[b*1024+vd][s] ----------------
__global__ __launch_bounds__(256) void vtrans(const u16* __restrict__ QKV, u16* __restrict__ Vt){
  __shared__ __align__(16) u16 t[64][65];
  int stile = blockIdx.x;                 // 0..31
  int b = blockIdx.y >> 4, vt = blockIdx.y & 15;
  int s0 = stile * 64, c0 = vt * 64;
  int lx = threadIdx.x & 15, ly = threadIdx.x >> 4;
  #pragma unroll
  for (int rr = 0; rr < 4; ++rr){
    int r = rr * 16 + ly;                 // s-row
    ushort4 v = *(const ushort4*)(QKV + (size_t)(b*S_ + s0 + r) * QSTR + 5120 + c0 + lx*4);
    t[lx*4+0][r]=v.x; t[lx*4+1][r]=v.y; t[lx*4+2][r]=v.z; t[lx*4+3][r]=v.w;
  }
  __syncthreads();
  #pragma unroll
  for (int rr = 0; rr < 4; ++rr){
    int r = rr * 16 + ly;                 // vd-row
    ushort4 o;
    o.x=t[r][lx*4+0]; o.y=t[r][lx*4+1]; o.z=t[r][lx*4+2]; o.w=t[r][lx*4+3];
    *(ushort4*)(Vt + (size_t)(b*1024 + c0 + r) * S_ + s0 + lx*4) = o;
  }
}

// ---------------- GEMM: C[M,N] = A[M,Kd](bf16) @ Bt[N,Kd]^T(bf16), m97 structure ----------------
template<bool OUTF32>
__global__ __launch_bounds__(256) void gemm_bt(const u16* __restrict__ A, const u16* __restrict__ Bt,
                                               void* __restrict__ C, int Nn, int Kd){
  __shared__ __align__(16) u16 As[128 * 32];
  __shared__ __align__(16) u16 Bs[128 * 32];
  const int tid = threadIdx.x;
  const int l = tid & 63, w = tid >> 6;
  const int wm = w >> 1, wn = w & 1;
  const int lr = l & 15, lk = l >> 4;
  const size_t arow0 = (size_t)blockIdx.x * 128;
  const size_t brow0 = (size_t)blockIdx.y * 128;
  const u16* Ag = A + arow0 * Kd;
  const u16* Bg = Bt + brow0 * Kd;

  f32x4 acc[4][4];
  #pragma unroll
  for (int i = 0; i < 4; ++i)
    #pragma unroll
    for (int j = 0; j < 4; ++j){ acc[i][j][0]=0.f; acc[i][j][1]=0.f; acc[i][j][2]=0.f; acc[i][j][3]=0.f; }

  const int nk = Kd >> 5;
  for (int kt = 0; kt < nk; ++kt){
    __syncthreads();
    #pragma unroll
    for (int c = 0; c < 2; ++c){
      int qbase = (c * 4 + w) * 64;
      int q = qbase + l;
      int r = q >> 2, kc = q & 3;
      gload_lds16(Ag + (size_t)r * Kd + kt * 32 + kc * 8, &As[qbase * 8]);
      gload_lds16(Bg + (size_t)r * Kd + kt * 32 + kc * 8, &Bs[qbase * 8]);
    }
    __syncthreads();

    bf16x8 af[4], bfr[4];
    #pragma unroll
    for (int mf = 0; mf < 4; ++mf)
      af[mf] = *(const bf16x8*)&As[(wm*64 + mf*16 + lr) * 32 + lk * 8];
    #pragma unroll
    for (int nf = 0; nf < 4; ++nf)
      bfr[nf] = *(const bf16x8*)&Bs[(wn*64 + nf*16 + lr) * 32 + lk * 8];
    #pragma unroll
    for (int mf = 0; mf < 4; ++mf)
      #pragma unroll
      for (int nf = 0; nf < 4; ++nf)
        acc[mf][nf] = __builtin_amdgcn_mfma_f32_16x16x32_bf16(af[mf], bfr[nf], acc[mf][nf], 0, 0, 0);
  }

  #pragma unroll
  for (int mf = 0; mf < 4; ++mf)
    #pragma unroll
    for (int nf = 0; nf < 4; ++nf)
      #pragma unroll
      for (int j = 0; j < 4; ++j){
        size_t gr = arow0 + wm*64 + mf*16 + lk*4 + j;
        size_t gc = brow0 + wn*64 + nf*16 + lr;
        float v = acc[mf][nf][j];
        if (OUTF32) ((float*)C)[gr * Nn + gc] = v;
        else        ((u16*)C)[gr * Nn + gc] = f2bf(v);
      }
}

// ---------------- RoPE in-place on bf16 [M_][stride] rows ----------------
__global__ void rope_k(u16* __restrict__ X, const int* __restrict__ pos, int hshift, int stride){
  int idx = blockIdx.x * 256 + threadIdx.x;
  int i = idx & 63;
  int h = (idx >> 6) & ((1 << hshift) - 1);
  int t = idx >> (6 + hshift);
  u16* p0 = X + (size_t)t * stride + h * D_ + i;
  float x1 = bf2f(p0[0]), x2 = bf2f(p0[64]);
  float fpos = (float)pos[t];
  float invf = exp2f(-(float)(2 * i) * (13.287712379549449f / 128.0f));
  float f = fpos * invf;
  float sv = __sinf(f), cv = __cosf(f);
  p0[0]  = f2bf(x1 * cv - x2 * sv);
  p0[64] = f2bf(x2 * cv + x1 * sv);
}

// ---------------- flash attention: 8 waves x 32 q-rows, KVBLK=64, 32x32x16 MFMA ----------------
// swapped QK^T (S^T, q = lane&31), O^T = mfma(V^T, P^T) so softmax state + acc are lane-local.
__global__ __launch_bounds__(512, 2) void attn_k(const u16* __restrict__ QKV,
                                                 const u16* __restrict__ Vtg,
                                                 u16* __restrict__ ctx){
  __shared__ __align__(16) u16 smem[32768];   // 64 KB: K dbuf [0,16384), Vt dbuf [16384,32768); epilogue overlay
  const int tid = threadIdx.x;
  const int l = tid & 63, w = tid >> 6;
  const int lane31 = l & 31, hi = l >> 5;
  const int hb = blockIdx.x;                  // b*32 + h
  const int b = hb >> 5, h = hb & 31, kvh = h >> 2;
  const int qb = 7 - blockIdx.y;              // heavy blocks dispatched first (LPT)
  const int q0w = qb * 256 + w * 32;
  const int qg = q0w + lane31;

  const u16* Qp = QKV + (size_t)b * S_ * QSTR + (size_t)h * D_;
  const char* Kp = (const char*)(QKV + (size_t)b * S_ * QSTR + 4096 + (size_t)kvh * D_);
  const char* Vp = (const char*)(Vtg + ((size_t)b * 1024 + kvh * 128) * S_);

  // Q B-fragments: Qf[dt] = Q[qg][dt*16 + hi*8 + j]
  bf16x8 qf[8];
  #pragma unroll
  for (int dt = 0; dt < 8; ++dt)
    qf[dt] = *(const bf16x8*)(Qp + (size_t)qg * QSTR + dt * 16 + hi * 8);

  // staging per-lane source offsets (pre-swizzled: LDS[r][x] = G[r][x ^ ((r&7)<<4)])
  const int krow0 = (2*w)*4 + (l >> 4), krow1 = krow0 + 4;
  const size_t koff0 = (size_t)krow0 * (QSTR*2) + (((l & 15) << 4) ^ ((krow0 & 7) << 4));
  const size_t koff1 = (size_t)krow1 * (QSTR*2) + (((l & 15) << 4) ^ ((krow1 & 7) << 4));
  const int vrow0 = (2*w)*8 + (l >> 3), vrow1 = vrow0 + 8;
  const size_t voff0 = (size_t)vrow0 * (S_*2) + (((l & 7) << 4) ^ ((vrow0 & 7) << 4));
  const size_t voff1 = (size_t)vrow1 * (S_*2) + (((l & 7) << 4) ^ ((vrow1 & 7) << 4));

  f32x16 acc[4];
  #pragma unroll
  for (int dt = 0; dt < 4; ++dt)
    #pragma unroll
    for (int i = 0; i < 16; ++i) acc[dt][i] = 0.f;
  float mrow = -3e38f, lsum = 0.f;

  const int nt = qb * 4 + 4;

  auto STAGE = [&](int t, int bufn){
    char* Kb = (char*)smem + bufn * 16384;
    char* Vb = (char*)smem + 32768 + bufn * 16384;
    size_t kb = (size_t)t * 64 * (QSTR*2);
    size_t vb = (size_t)t * 128;          // 64 k * 2B along S
    gload_lds16(Kp + kb + koff0, Kb + (2*w)*1024);
    gload_lds16(Kp + kb + koff1, Kb + (2*w+1)*1024);
    gload_lds16(Vp + vb + voff0, Vb + (2*w)*1024);
    gload_lds16(Vp + vb + voff1, Vb + (2*w+1)*1024);
  };

  STAGE(0, 0);
  __syncthreads();
  int buf = 0;
  for (int t = 0; t < nt; ++t){
    if (t + 1 < nt) STAGE(t + 1, buf ^ 1);
    const int kbase = t * 64;
    if (kbase <= q0w + 31){
      const char* Kb = (const char*)smem + buf * 16384;
      const char* Vb = (const char*)smem + 32768 + buf * 16384;
      const int swz = (lane31 & 7) << 4;

      // S^T = K Q^T : two 32-k tiles
      f32x16 s0, s1;
      #pragma unroll
      for (int i = 0; i < 16; ++i){ s0[i] = 0.f; s1[i] = 0.f; }
      #pragma unroll
      for (int dt = 0; dt < 8; ++dt){
        bf16x8 kf = *(const bf16x8*)(Kb + lane31*256 + ((dt*32 + hi*16) ^ swz));
        s0 = __builtin_amdgcn_mfma_f32_32x32x16_bf16(kf, qf[dt], s0, 0, 0, 0);
      }
      #pragma unroll
      for (int dt = 0; dt < 8; ++dt){
        bf16x8 kf = *(const bf16x8*)(Kb + (32 + lane31)*256 + ((dt*32 + hi*16) ^ swz));
        s1 = __builtin_amdgcn_mfma_f32_32x32x16_bf16(kf, qf[dt], s1, 0, 0, 0);
      }

      // causal mask (only straddling tiles)
      if (kbase + 63 > q0w){
        int thr = qg - kbase;
        #pragma unroll
        for (int r = 0; r < 16; ++r){
          int kc = (r & 3) + 8*(r >> 2) + 4*hi;
          s0[r] = (kc > thr)      ? -1e30f : s0[r];
          s1[r] = (kc + 32 > thr) ? -1e30f : s1[r];
        }
      }

      // online softmax (per-lane, q = lane31; combine halves via shfl_xor 32)
      float tmax = s0[0];
      #pragma unroll
      for (int r = 1; r < 16; ++r) tmax = fmaxf(tmax, s0[r]);
      #pragma unroll
      for (int r = 0; r < 16; ++r) tmax = fmaxf(tmax, s1[r]);
      tmax = fmaxf(tmax, __shfl_xor(tmax, 32));
      float mn = fmaxf(mrow, tmax);
      float rf = exp2f((mrow - mn) * KSC);
      mrow = mn;
      float ps = 0.f;
      #pragma unroll
      for (int r = 0; r < 16; ++r){
        float a = exp2f((s0[r] - mn) * KSC);
        float c = exp2f((s1[r] - mn) * KSC);
        s0[r] = a; s1[r] = c; ps += a + c;
      }
      ps += __shfl_xor(ps, 32);
      lsum = lsum * rf + ps;
      #pragma unroll
      for (int dt = 0; dt < 4; ++dt)
        #pragma unroll
        for (int i = 0; i < 16; ++i) acc[dt][i] *= rf;

      // pack P to bf16 words: pw[st*8 + m]; lane's word m covers k = 4m..(+1) pattern
      u32 pw[16];
      #pragma unroll
      for (int g = 0; g < 4; ++g){
        pw[2*g]     = (u32)f2bf(s0[4*g])   | ((u32)f2bf(s0[4*g+1]) << 16);
        pw[2*g+1]   = (u32)f2bf(s0[4*g+2]) | ((u32)f2bf(s0[4*g+3]) << 16);
        pw[8+2*g]   = (u32)f2bf(s1[4*g])   | ((u32)f2bf(s1[4*g+1]) << 16);
        pw[8+2*g+1] = (u32)f2bf(s1[4*g+2]) | ((u32)f2bf(s1[4*g+3]) << 16);
      }

      // O^T += V^T P^T : per 16-k subtile, exchange half-lane words to build P B-frag
      #pragma unroll
      for (int kt = 0; kt < 4; ++kt){
        u32 W0 = pw[kt*4+0], W1 = pw[kt*4+1], W2 = pw[kt*4+2], W3 = pw[kt*4+3];
        u32 x0 = hi ? W0 : W2;
        u32 x1 = hi ? W1 : W3;
        u32 y0 = __shfl_xor(x0, 32);
        u32 y1 = __shfl_xor(x1, 32);
        u32 w0 = hi ? y0 : W0;
        u32 w1 = hi ? y1 : W1;
        u32 w2 = hi ? W2 : y0;
        u32 w3 = hi ? W3 : y1;
        u32x4 pk; pk[0]=w0; pk[1]=w1; pk[2]=w2; pk[3]=w3;
        bf16x8 pa = __builtin_bit_cast(bf16x8, pk);
        #pragma unroll
        for (int dt = 0; dt < 4; ++dt){
          bf16x8 vf = *(const bf16x8*)(Vb + (dt*32 + lane31)*128 + ((kt*32 + hi*16) ^ swz));
          acc[dt] = __builtin_amdgcn_mfma_f32_32x32x16_bf16(vf, pa, acc[dt], 0, 0, 0);
        }
      }
    }
    __syncthreads();
    buf ^= 1;
  }

  // epilogue: O^T regs -> swizzled LDS [32 q][128 d] per wave -> coalesced bf16 stores
  __syncthreads();
  u16* Ot = smem + w * 4096;
  float inv = 1.f / lsum;
  #pragma unroll
  for (int dt = 0; dt < 4; ++dt)
    #pragma unroll
    for (int r = 0; r < 16; ++r){
      int d = dt*32 + (r & 3) + 8*(r >> 2) + 4*hi;
      Ot[lane31*128 + (d ^ ((lane31 & 15) << 2))] = f2bf(acc[dt][r] * inv);
    }
  u16* outp = ctx + ((size_t)(b * S_ + q0w)) * HID_ + h * D_;
  #pragma unroll
  for (int it = 0; it < 16; ++it){
    int id = it * 64 + l;
    int q = id >> 5;
    int c4 = (id & 31) * 4;
    ushort4 vv = *(const ushort4*)(Ot + q*128 + (c4 ^ ((q & 15) << 2)));
    *(ushort4*)(outp + (size_t)q * HID_ + c4) = vv;
  }
}

extern "C" void kernel_launch(void* const* d_in, const int* in_sizes, int n_in,
                              void* d_out, int out_size, void* d_ws, size_t ws_size,
                              hipStream_t stream) {
  const float* x  = (const float*)d_in[0];
  const int*   pos = (const int*)d_in[2];
  const float* Wq = (const float*)d_in[3];
  const float* Wk = (const float*)d_in[4];
  const float* Wv = (const float*)d_in[5];
  const float* Wo = (const float*)d_in[6];

  char* ws = (char*)d_ws;
  u16* xb   = (u16*)(ws);                               // 32MB; reused as ctx after QKV
  u16* WT   = (u16*)(ws + ((size_t)32 << 20));          // 48MB: Wq^T|Wk^T|Wv^T (dead after QKV gemm)
  u16* WoT  = (u16*)(ws + ((size_t)80 << 20));          // 32MB
  u16* QKVb = (u16*)(ws + ((size_t)112 << 20));         // 48MB: [4096][6144]
  u16* Vtg  = (u16*)(ws + ((size_t)32 << 20));          // 8MB overlay on WT: [b*1024+vd][S]

  cast_f32_bf16<<<16384, 256, 0, stream>>>(x, xb, HID_ * M_);
  tcast<<<dim3(64, 64), 256, 0, stream>>>(Wq, WT, 4096, 4096);
  tcast<<<dim3(64, 16), 256, 0, stream>>>(Wk, WT + (size_t)4096 * 4096, 4096, 1024);
  tcast<<<dim3(64, 16), 256, 0, stream>>>(Wv, WT + (size_t)5120 * 4096, 4096, 1024);
  tcast<<<dim3(64, 64), 256, 0, stream>>>(Wo, WoT, 4096, 4096);
  gemm_bt<false><<<dim3(32, 48), 256, 0, stream>>>(xb, WT, QKVb, 6144, 4096);
  rope_k<<<32768, 256, 0, stream>>>(QKVb,        pos, 5, QSTR);
  rope_k<<<8192,  256, 0, stream>>>(QKVb + 4096, pos, 3, QSTR);
  vtrans<<<dim3(32, 32), 256, 0, stream>>>(QKVb, Vtg);
  attn_k<<<dim3(64, 8), 512, 0, stream>>>(QKVb, Vtg, xb);
  gemm_bt<true><<<dim3(32, 32), 256, 0, stream>>>(xb, WoT, d_out, 4096, 4096);
}

// Round 3
// 588.332 us; speedup vs baseline: 2.4044x; 1.1296x over previous
//
#include <hip/hip_runtime.h>
#include <cstdint>
#include <cstddef>

#define B_   2
#define S_   2048
#define HID_ 4096
#define H_   32
#define KV_  8
#define D_   128
#define M_   (B_*S_)      // 4096 tokens
#define QSTR 6144         // QKV combined row stride (H*D + 2*KV*D)

typedef __attribute__((ext_vector_type(8))) short bf16x8;
typedef __attribute__((ext_vector_type(4))) float f32x4;
typedef __attribute__((ext_vector_type(16))) float f32x16;
typedef __attribute__((ext_vector_type(4))) unsigned int u32x4;
typedef unsigned short u16;
typedef unsigned int   u32;

// softmax scale folded into exp2: SCALE * log2(e)
#define KSC (0.08838834764831845f * 1.4426950408889634f)

__device__ __forceinline__ float bf2f(u16 v){ u32 u = ((u32)v) << 16; return __builtin_bit_cast(float, u); }
__device__ __forceinline__ u16 f2bf(float f){
  u32 u = __builtin_bit_cast(u32, f);
  u32 r = u + 0x7fffu + ((u >> 16) & 1u);   // RNE
  return (u16)(r >> 16);
}

__device__ __forceinline__ void gload_lds16(const void* g, void* lds){
  __builtin_amdgcn_global_load_lds(
      (const __attribute__((address_space(1))) void*)g,
      (__attribute__((address_space(3))) void*)lds, 16, 0, 0);
}

// ---------------- cast fp32 -> bf16 (vectorized) ----------------
__global__ void cast_f32_bf16(const float* __restrict__ in, u16* __restrict__ out, int n){
  int i = (blockIdx.x * blockDim.x + threadIdx.x) * 4;
  if (i >= n) return;
  float4 v = *(const float4*)(in + i);
  ushort4 o;
  o.x = f2bf(v.x); o.y = f2bf(v.y); o.z = f2bf(v.z); o.w = f2bf(v.w);
  *(ushort4*)(out + i) = o;
}

// ---------------- transpose-cast: W[Kd][Nd] fp32 -> WT[Nd][Kd] bf16 ----------------
__global__ __launch_bounds__(256) void tcast(const float* __restrict__ W, u16* __restrict__ WT,
                                             int Kd, int Nd){
  __shared__ __align__(16) u16 t[64][65];     // t[n][k]
  int k0 = blockIdx.x * 64, n0 = blockIdx.y * 64;
  int lx = threadIdx.x & 15, ly = threadIdx.x >> 4;
  #pragma unroll
  for (int rr = 0; rr < 4; ++rr){
    int r = rr * 16 + ly;                     // k-row in tile
    float4 v = *(const float4*)(W + (size_t)(k0 + r) * Nd + n0 + lx * 4);
    t[lx*4+0][r] = f2bf(v.x);
    t[lx*4+1][r] = f2bf(v.y);
    t[lx*4+2][r] = f2bf(v.z);
    t[lx*4+3][r] = f2bf(v.w);
  }
  __syncthreads();
  #pragma unroll
  for (int rr = 0; rr < 4; ++rr){
    int r = rr * 16 + ly;                     // n-row in tile
    ushort4 o;
    o.x = t[r][lx*4+0]; o.y = t[r][lx*4+1]; o.z = t[r][lx*4+2]; o.w = t[r][lx*4+3];
    *(ushort4*)(WT + (size_t)(n0 + r) * Kd + k0 + lx * 4) = o;
  }
}

// ---------------- transpose V (bf16): QKV[t][5120 + vd] -> Vt[b*1024+vd][s] ----------------
__global__ __launch_bounds__(256) void vtrans(const u16* __restrict__ QKV, u16* __restrict__ Vt){
  __shared__ __align__(16) u16 t[64][65];
  int stile = blockIdx.x;                 // 0..31
  int b = blockIdx.y >> 4, vt = blockIdx.y & 15;
  int s0 = stile * 64, c0 = vt * 64;
  int lx = threadIdx.x & 15, ly = threadIdx.x >> 4;
  #pragma unroll
  for (int rr = 0; rr < 4; ++rr){
    int r = rr * 16 + ly;                 // s-row
    ushort4 v = *(const ushort4*)(QKV + (size_t)(b*S_ + s0 + r) * QSTR + 5120 + c0 + lx*4);
    t[lx*4+0][r]=v.x; t[lx*4+1][r]=v.y; t[lx*4+2][r]=v.z; t[lx*4+3][r]=v.w;
  }
  __syncthreads();
  #pragma unroll
  for (int rr = 0; rr < 4; ++rr){
    int r = rr * 16 + ly;                 // vd-row
    ushort4 o;
    o.x=t[r][lx*4+0]; o.y=t[r][lx*4+1]; o.z=t[r][lx*4+2]; o.w=t[r][lx*4+3];
    *(ushort4*)(Vt + (size_t)(b*1024 + c0 + r) * S_ + s0 + lx*4) = o;
  }
}

// ---------------- RoPE in-place on bf16 [M_][stride] rows ----------------
__global__ void rope_k(u16* __restrict__ X, const int* __restrict__ pos, int hshift, int stride){
  int idx = blockIdx.x * 256 + threadIdx.x;
  int i = idx & 63;
  int h = (idx >> 6) & ((1 << hshift) - 1);
  int t = idx >> (6 + hshift);
  u16* p0 = X + (size_t)t * stride + h * D_ + i;
  float x1 = bf2f(p0[0]), x2 = bf2f(p0[64]);
  float fpos = (float)pos[t];
  float invf = exp2f(-(float)(2 * i) * (13.287712379549449f / 128.0f));
  float f = fpos * invf;
  float sv = __sinf(f), cv = __cosf(f);
  p0[0]  = f2bf(x1 * cv - x2 * sv);
  p0[64] = f2bf(x2 * cv + x1 * sv);
}

// ============ 256x256 8-phase GEMM (K=4096): C[M,N] = A[M,4096] @ Bt[N,4096]^T ============
// 8 waves (2Mx4N), BK=64, 128KB LDS double-buffer, chunk-XOR swizzle, counted vmcnt(4),
// raw barriers + sched_barrier fences, setprio around MFMA.  [guide §5 8-phase template]

#define SBAR() __builtin_amdgcn_sched_barrier(0)
#define BARX() do{ SBAR(); __builtin_amdgcn_s_barrier(); SBAR(); }while(0)

// stage one 128-row half-tile (2 x global_load_lds per thread)
#define STG_A(PB, HALF, KT) do{ \
  gload_lds16(Ag + off0 + (size_t)(HALF)*1048576 + (size_t)(KT)*128, \
              (char*)smem + (PB)*32768 + (HALF)*16384 + w*1024); \
  gload_lds16(Ag + off0 + 524288 + (size_t)(HALF)*1048576 + (size_t)(KT)*128, \
              (char*)smem + (PB)*32768 + (HALF)*16384 + 8192 + w*1024); }while(0)
#define STG_B(PB, HALF, KT) do{ \
  gload_lds16(Bg + off0 + (size_t)(HALF)*1048576 + (size_t)(KT)*128, \
              (char*)smem + 65536 + (PB)*32768 + (HALF)*16384 + w*1024); \
  gload_lds16(Bg + off0 + 524288 + (size_t)(HALF)*1048576 + (size_t)(KT)*128, \
              (char*)smem + 65536 + (PB)*32768 + (HALF)*16384 + 8192 + w*1024); }while(0)

// one phase: 12 ds_read_b128 + stage issue + barrier + 16 MFMA (one block C-quadrant x K=64)
#define PHASE(P, MH, NH, ...) do{                                        \
  bf16x8 afr[2][4], bfr2[2][2];                                          \
  _Pragma("unroll") for (int ks = 0; ks < 2; ++ks){                      \
    _Pragma("unroll") for (int m = 0; m < 4; ++m)                        \
      afr[ks][m] = *(const bf16x8*)&smem[(P)*16384 + (MH)*8192 + aRowBase + m*1024 + csw[ks]]; \
    _Pragma("unroll") for (int n = 0; n < 2; ++n)                        \
      bfr2[ks][n] = *(const bf16x8*)&smem[32768 + (P)*16384 + (NH)*8192 + bRowBase + n*1024 + csw[ks]]; \
  }                                                                      \
  __VA_ARGS__;                                                           \
  BARX();                                                                \
  __builtin_amdgcn_s_setprio(1);                                         \
  _Pragma("unroll") for (int ks = 0; ks < 2; ++ks)                       \
    _Pragma("unroll") for (int m = 0; m < 4; ++m)                        \
      _Pragma("unroll") for (int n = 0; n < 2; ++n)                      \
        acc[(MH)*4+m][(NH)*2+n] = __builtin_amdgcn_mfma_f32_16x16x32_bf16(afr[ks][m], bfr2[ks][n], acc[(MH)*4+m][(NH)*2+n], 0, 0, 0); \
  __builtin_amdgcn_s_setprio(0);                                         \
}while(0)

template<bool OUTF32>
__global__ __launch_bounds__(512, 2) void gemm256(const u16* __restrict__ A, const u16* __restrict__ Bt,
                                                  void* __restrict__ C, int Nn, int mt){
  __shared__ __align__(16) u16 smem[65536];   // 128 KB: As[2] [0,32768)B, Bs[2] [65536,131072)B
  const int tid = threadIdx.x;
  const int l = tid & 63, w = tid >> 6;
  const int lr = l & 15, lk = l >> 4;
  const int wr = w >> 2, wc = w & 3;

  // bijective XCD swizzle (nwg % 8 == 0 for both grids)
  const int nwg = gridDim.x;
  const int sbid = ((int)blockIdx.x & 7) * (nwg >> 3) + ((int)blockIdx.x >> 3);
  const int bx = sbid % mt, by = sbid / mt;
  const size_t arow0 = (size_t)bx * 256;
  const size_t brow0 = (size_t)by * 256;
  const char* Ag = (const char*)(A + arow0 * 4096);
  const char* Bg = (const char*)(Bt + brow0 * 4096);

  // per-thread staging source offset (row = w*8 + l/8, chunk = (l&7) ^ (row&7); issue1 = +64 rows)
  const size_t off0 = (size_t)(w * 8 + (l >> 3)) * 8192 + (size_t)(((l & 7) ^ (l >> 3)) << 4);

  // ds_read bases (u16 units): row*64 + swizzled-chunk*8
  const int aRowBase = (wr*64 + lr) * 64;
  const int bRowBase = (wc*32 + lr) * 64;
  int csw[2];
  csw[0] = ((lk     ) ^ (lr & 7)) << 3;
  csw[1] = ((lk + 4) ^ (lr & 7)) << 3;

  f32x4 acc[8][4];
  #pragma unroll
  for (int i = 0; i < 8; ++i)
    #pragma unroll
    for (int j = 0; j < 4; ++j){ acc[i][j][0]=0.f; acc[i][j][1]=0.f; acc[i][j][2]=0.f; acc[i][j][3]=0.f; }

  // prologue: tile0 all 4 halves, then tile1 B0,A0  (12 loads; vmcnt(4) leaves newest 2 halves in flight)
  STG_A(0, 0, 0); STG_B(0, 0, 0);
  STG_A(0, 1, 0); STG_B(0, 1, 0);
  STG_B(1, 0, 1); STG_A(1, 0, 1);
  asm volatile("s_waitcnt vmcnt(4)" ::: "memory");
  BARX();

  for (int t = 0; t < 64; ++t){
    const int P = t & 1;
    PHASE(P, 0, 0, { if (t < 63){ STG_A(P^1, 1, t+1); STG_B(P^1, 1, t+1); } });
    BARX();
    PHASE(P, 1, 0, {});
    BARX();
    PHASE(P, 0, 1, { if (t < 62){ STG_B(P, 0, t+2); } });
    BARX();
    PHASE(P, 1, 1, { if (t < 62){ STG_A(P, 0, t+2); } });
    if (t < 62) asm volatile("s_waitcnt vmcnt(4)" ::: "memory");
    else        asm volatile("s_waitcnt vmcnt(0)" ::: "memory");
    BARX();
  }

  // epilogue: C row = ... + lk*4 + j, col = ... + lr  [m89 layout, validated R2]
  #pragma unroll
  for (int mh = 0; mh < 2; ++mh)
    #pragma unroll
    for (int m = 0; m < 4; ++m)
      #pragma unroll
      for (int nh = 0; nh < 2; ++nh)
        #pragma unroll
        for (int n = 0; n < 2; ++n)
          #pragma unroll
          for (int j = 0; j < 4; ++j){
            size_t gr = arow0 + mh*128 + wr*64 + m*16 + lk*4 + j;
            size_t gc = brow0 + nh*128 + wc*32 + n*16 + lr;
            float v = acc[mh*4+m][nh*2+n][j];
            if (OUTF32) ((float*)C)[gr * Nn + gc] = v;
            else        ((u16*)C)[gr * Nn + gc] = f2bf(v);
          }
}

// ---------------- flash attention: 8 waves x 32 q-rows, KVBLK=64, 32x32x16 MFMA ----------------
__global__ __launch_bounds__(512, 2) void attn_k(const u16* __restrict__ QKV,
                                                 const u16* __restrict__ Vtg,
                                                 u16* __restrict__ ctx){
  __shared__ __align__(16) u16 smem[32768];   // 64 KB
  const int tid = threadIdx.x;
  const int l = tid & 63, w = tid >> 6;
  const int lane31 = l & 31, hi = l >> 5;
  const int hb = blockIdx.x;
  const int b = hb >> 5, h = hb & 31, kvh = h >> 2;
  const int qb = 7 - blockIdx.y;              // LPT
  const int q0w = qb * 256 + w * 32;
  const int qg = q0w + lane31;

  const u16* Qp = QKV + (size_t)b * S_ * QSTR + (size_t)h * D_;
  const char* Kp = (const char*)(QKV + (size_t)b * S_ * QSTR + 4096 + (size_t)kvh * D_);
  const char* Vp = (const char*)(Vtg + ((size_t)b * 1024 + kvh * 128) * S_);

  bf16x8 qf[8];
  #pragma unroll
  for (int dt = 0; dt < 8; ++dt)
    qf[dt] = *(const bf16x8*)(Qp + (size_t)qg * QSTR + dt * 16 + hi * 8);

  const int krow0 = (2*w)*4 + (l >> 4), krow1 = krow0 + 4;
  const size_t koff0 = (size_t)krow0 * (QSTR*2) + (((l & 15) << 4) ^ ((krow0 & 7) << 4));
  const size_t koff1 = (size_t)krow1 * (QSTR*2) + (((l & 15) << 4) ^ ((krow1 & 7) << 4));
  const int vrow0 = (2*w)*8 + (l >> 3), vrow1 = vrow0 + 8;
  const size_t voff0 = (size_t)vrow0 * (S_*2) + (((l & 7) << 4) ^ ((vrow0 & 7) << 4));
  const size_t voff1 = (size_t)vrow1 * (S_*2) + (((l & 7) << 4) ^ ((vrow1 & 7) << 4));

  f32x16 acc[4];
  #pragma unroll
  for (int dt = 0; dt < 4; ++dt)
    #pragma unroll
    for (int i = 0; i < 16; ++i) acc[dt][i] = 0.f;
  float mrow = -3e38f, lsum = 0.f;

  const int nt = qb * 4 + 4;

  auto STAGE = [&](int t, int bufn){
    char* Kb = (char*)smem + bufn * 16384;
    char* Vb = (char*)smem + 32768 + bufn * 16384;
    size_t kb = (size_t)t * 64 * (QSTR*2);
    size_t vb = (size_t)t * 128;
    gload_lds16(Kp + kb + koff0, Kb + (2*w)*1024);
    gload_lds16(Kp + kb + koff1, Kb + (2*w+1)*1024);
    gload_lds16(Vp + vb + voff0, Vb + (2*w)*1024);
    gload_lds16(Vp + vb + voff1, Vb + (2*w+1)*1024);
  };

  STAGE(0, 0);
  __syncthreads();
  int buf = 0;
  for (int t = 0; t < nt; ++t){
    if (t + 1 < nt) STAGE(t + 1, buf ^ 1);
    const int kbase = t * 64;
    if (kbase <= q0w + 31){
      const char* Kb = (const char*)smem + buf * 16384;
      const char* Vb = (const char*)smem + 32768 + buf * 16384;
      const int swz = (lane31 & 7) << 4;

      f32x16 s0, s1;
      #pragma unroll
      for (int i = 0; i < 16; ++i){ s0[i] = 0.f; s1[i] = 0.f; }
      #pragma unroll
      for (int dt = 0; dt < 8; ++dt){
        bf16x8 kf = *(const bf16x8*)(Kb + lane31*256 + ((dt*32 + hi*16) ^ swz));
        s0 = __builtin_amdgcn_mfma_f32_32x32x16_bf16(kf, qf[dt], s0, 0, 0, 0);
      }
      #pragma unroll
      for (int dt = 0; dt < 8; ++dt){
        bf16x8 kf = *(const bf16x8*)(Kb + (32 + lane31)*256 + ((dt*32 + hi*16) ^ swz));
        s1 = __builtin_amdgcn_mfma_f32_32x32x16_bf16(kf, qf[dt], s1, 0, 0, 0);
      }

      if (kbase + 63 > q0w){
        int thr = qg - kbase;
        #pragma unroll
        for (int r = 0; r < 16; ++r){
          int kc = (r & 3) + 8*(r >> 2) + 4*hi;
          s0[r] = (kc > thr)      ? -1e30f : s0[r];
          s1[r] = (kc + 32 > thr) ? -1e30f : s1[r];
        }
      }

      float tmax = s0[0];
      #pragma unroll
      for (int r = 1; r < 16; ++r) tmax = fmaxf(tmax, s0[r]);
      #pragma unroll
      for (int r = 0; r < 16; ++r) tmax = fmaxf(tmax, s1[r]);
      tmax = fmaxf(tmax, __shfl_xor(tmax, 32));
      float mn = fmaxf(mrow, tmax);
      float rf = exp2f((mrow - mn) * KSC);
      mrow = mn;
      float ps = 0.f;
      #pragma unroll
      for (int r = 0; r < 16; ++r){
        float a = exp2f((s0[r] - mn) * KSC);
        float c = exp2f((s1[r] - mn) * KSC);
        s0[r] = a; s1[r] = c; ps += a + c;
      }
      ps += __shfl_xor(ps, 32);
      lsum = lsum * rf + ps;
      #pragma unroll
      for (int dt = 0; dt < 4; ++dt)
        #pragma unroll
        for (int i = 0; i < 16; ++i) acc[dt][i] *= rf;

      u32 pw[16];
      #pragma unroll
      for (int g = 0; g < 4; ++g){
        pw[2*g]     = (u32)f2bf(s0[4*g])   | ((u32)f2bf(s0[4*g+1]) << 16);
        pw[2*g+1]   = (u32)f2bf(s0[4*g+2]) | ((u32)f2bf(s0[4*g+3]) << 16);
        pw[8+2*g]   = (u32)f2bf(s1[4*g])   | ((u32)f2bf(s1[4*g+1]) << 16);
        pw[8+2*g+1] = (u32)f2bf(s1[4*g+2]) | ((u32)f2bf(s1[4*g+3]) << 16);
      }

      #pragma unroll
      for (int kt = 0; kt < 4; ++kt){
        u32 W0 = pw[kt*4+0], W1 = pw[kt*4+1], W2 = pw[kt*4+2], W3 = pw[kt*4+3];
        u32 x0 = hi ? W0 : W2;
        u32 x1 = hi ? W1 : W3;
        u32 y0 = __shfl_xor(x0, 32);
        u32 y1 = __shfl_xor(x1, 32);
        u32 w0 = hi ? y0 : W0;
        u32 w1 = hi ? y1 : W1;
        u32 w2 = hi ? W2 : y0;
        u32 w3 = hi ? W3 : y1;
        u32x4 pk; pk[0]=w0; pk[1]=w1; pk[2]=w2; pk[3]=w3;
        bf16x8 pa = __builtin_bit_cast(bf16x8, pk);
        #pragma unroll
        for (int dt = 0; dt < 4; ++dt){
          bf16x8 vf = *(const bf16x8*)(Vb + (dt*32 + lane31)*128 + ((kt*32 + hi*16) ^ swz));
          acc[dt] = __builtin_amdgcn_mfma_f32_32x32x16_bf16(vf, pa, acc[dt], 0, 0, 0);
        }
      }
    }
    __syncthreads();
    buf ^= 1;
  }

  __syncthreads();
  u16* Ot = smem + w * 4096;
  float inv = 1.f / lsum;
  #pragma unroll
  for (int dt = 0; dt < 4; ++dt)
    #pragma unroll
    for (int r = 0; r < 16; ++r){
      int d = dt*32 + (r & 3) + 8*(r >> 2) + 4*hi;
      Ot[lane31*128 + (d ^ ((lane31 & 15) << 2))] = f2bf(acc[dt][r] * inv);
    }
  u16* outp = ctx + ((size_t)(b * S_ + q0w)) * HID_ + h * D_;
  #pragma unroll
  for (int it = 0; it < 16; ++it){
    int id = it * 64 + l;
    int q = id >> 5;
    int c4 = (id & 31) * 4;
    ushort4 vv = *(const ushort4*)(Ot + q*128 + (c4 ^ ((q & 15) << 2)));
    *(ushort4*)(outp + (size_t)q * HID_ + c4) = vv;
  }
}

extern "C" void kernel_launch(void* const* d_in, const int* in_sizes, int n_in,
                              void* d_out, int out_size, void* d_ws, size_t ws_size,
                              hipStream_t stream) {
  const float* x  = (const float*)d_in[0];
  const int*   pos = (const int*)d_in[2];
  const float* Wq = (const float*)d_in[3];
  const float* Wk = (const float*)d_in[4];
  const float* Wv = (const float*)d_in[5];
  const float* Wo = (const float*)d_in[6];

  char* ws = (char*)d_ws;
  u16* xb   = (u16*)(ws);                               // 32MB; reused as ctx after QKV
  u16* WT   = (u16*)(ws + ((size_t)32 << 20));          // 48MB: Wq^T|Wk^T|Wv^T (dead after QKV gemm)
  u16* WoT  = (u16*)(ws + ((size_t)80 << 20));          // 32MB
  u16* QKVb = (u16*)(ws + ((size_t)112 << 20));         // 48MB: [4096][6144]
  u16* Vtg  = (u16*)(ws + ((size_t)32 << 20));          // 8MB overlay on WT: [b*1024+vd][S]

  cast_f32_bf16<<<16384, 256, 0, stream>>>(x, xb, HID_ * M_);
  tcast<<<dim3(64, 64), 256, 0, stream>>>(Wq, WT, 4096, 4096);
  tcast<<<dim3(64, 16), 256, 0, stream>>>(Wk, WT + (size_t)4096 * 4096, 4096, 1024);
  tcast<<<dim3(64, 16), 256, 0, stream>>>(Wv, WT + (size_t)5120 * 4096, 4096, 1024);
  tcast<<<dim3(64, 64), 256, 0, stream>>>(Wo, WoT, 4096, 4096);
  gemm256<false><<<16 * 24, 512, 0, stream>>>(xb, WT, QKVb, 6144, 16);
  rope_k<<<32768, 256, 0, stream>>>(QKVb,        pos, 5, QSTR);
  rope_k<<<8192,  256, 0, stream>>>(QKVb + 4096, pos, 3, QSTR);
  vtrans<<<dim3(32, 32), 256, 0, stream>>>(QKVb, Vtg);
  attn_k<<<dim3(64, 8), 512, 0, stream>>>(QKVb, Vtg, xb);
  gemm256<true><<<16 * 16, 512, 0, stream>>>(xb, WoT, d_out, 4096, 16);
}

// Round 4
// 546.871 us; speedup vs baseline: 2.5866x; 1.0758x over previous
//
#include <hip/hip_runtime.h>
#include <cstdint>
#include <cstddef>

#define B_   2
#define S_   2048
#define HID_ 4096
#define H_   32
#define KV_  8
#define D_   128
#define M_   (B_*S_)      // 4096 tokens
#define QSTR 6144         // QKV combined row stride (H*D + 2*KV*D)

typedef __attribute__((ext_vector_type(8))) short bf16x8;
typedef __attribute__((ext_vector_type(4))) float f32x4;
typedef __attribute__((ext_vector_type(16))) float f32x16;
typedef __attribute__((ext_vector_type(4))) unsigned int u32x4;
typedef unsigned short u16;
typedef unsigned int   u32;

// softmax scale folded into exp2: SCALE * log2(e)
#define KSC (0.08838834764831845f * 1.4426950408889634f)

__device__ __forceinline__ float bf2f(u16 v){ u32 u = ((u32)v) << 16; return __builtin_bit_cast(float, u); }
__device__ __forceinline__ u16 f2bf(float f){
  u32 u = __builtin_bit_cast(u32, f);
  u32 r = u + 0x7fffu + ((u >> 16) & 1u);   // RNE
  return (u16)(r >> 16);
}

__device__ __forceinline__ void gload_lds16(const void* g, void* lds){
  __builtin_amdgcn_global_load_lds(
      (const __attribute__((address_space(1))) void*)g,
      (__attribute__((address_space(3))) void*)lds, 16, 0, 0);
}

// ---------------- cast fp32 -> bf16 (vectorized) ----------------
__global__ void cast_f32_bf16(const float* __restrict__ in, u16* __restrict__ out, int n){
  int i = (blockIdx.x * blockDim.x + threadIdx.x) * 4;
  if (i >= n) return;
  float4 v = *(const float4*)(in + i);
  ushort4 o;
  o.x = f2bf(v.x); o.y = f2bf(v.y); o.z = f2bf(v.z); o.w = f2bf(v.w);
  *(ushort4*)(out + i) = o;
}

// ---------------- transpose-cast: W[Kd][Nd] fp32 -> WT[Nd][Kd] bf16 ----------------
__global__ __launch_bounds__(256) void tcast(const float* __restrict__ W, u16* __restrict__ WT,
                                             int Kd, int Nd){
  __shared__ __align__(16) u16 t[64][65];     // t[n][k]
  int k0 = blockIdx.x * 64, n0 = blockIdx.y * 64;
  int lx = threadIdx.x & 15, ly = threadIdx.x >> 4;
  #pragma unroll
  for (int rr = 0; rr < 4; ++rr){
    int r = rr * 16 + ly;                     // k-row in tile
    float4 v = *(const float4*)(W + (size_t)(k0 + r) * Nd + n0 + lx * 4);
    t[lx*4+0][r] = f2bf(v.x);
    t[lx*4+1][r] = f2bf(v.y);
    t[lx*4+2][r] = f2bf(v.z);
    t[lx*4+3][r] = f2bf(v.w);
  }
  __syncthreads();
  #pragma unroll
  for (int rr = 0; rr < 4; ++rr){
    int r = rr * 16 + ly;                     // n-row in tile
    ushort4 o;
    o.x = t[r][lx*4+0]; o.y = t[r][lx*4+1]; o.z = t[r][lx*4+2]; o.w = t[r][lx*4+3];
    *(ushort4*)(WT + (size_t)(n0 + r) * Kd + k0 + lx * 4) = o;
  }
}

// ---------------- transpose V (bf16): QKV[t][5120 + vd] -> Vt[b*1024+vd][s] ----------------
__global__ __launch_bounds__(256) void vtrans(const u16* __restrict__ QKV, u16* __restrict__ Vt){
  __shared__ __align__(16) u16 t[64][65];
  int stile = blockIdx.x;                 // 0..31
  int b = blockIdx.y >> 4, vt = blockIdx.y & 15;
  int s0 = stile * 64, c0 = vt * 64;
  int lx = threadIdx.x & 15, ly = threadIdx.x >> 4;
  #pragma unroll
  for (int rr = 0; rr < 4; ++rr){
    int r = rr * 16 + ly;                 // s-row
    ushort4 v = *(const ushort4*)(QKV + (size_t)(b*S_ + s0 + r) * QSTR + 5120 + c0 + lx*4);
    t[lx*4+0][r]=v.x; t[lx*4+1][r]=v.y; t[lx*4+2][r]=v.z; t[lx*4+3][r]=v.w;
  }
  __syncthreads();
  #pragma unroll
  for (int rr = 0; rr < 4; ++rr){
    int r = rr * 16 + ly;                 // vd-row
    ushort4 o;
    o.x=t[r][lx*4+0]; o.y=t[r][lx*4+1]; o.z=t[r][lx*4+2]; o.w=t[r][lx*4+3];
    *(ushort4*)(Vt + (size_t)(b*1024 + c0 + r) * S_ + s0 + lx*4) = o;
  }
}

// ---------------- RoPE in-place on bf16 [M_][stride] rows ----------------
__global__ void rope_k(u16* __restrict__ X, const int* __restrict__ pos, int hshift, int stride){
  int idx = blockIdx.x * 256 + threadIdx.x;
  int i = idx & 63;
  int h = (idx >> 6) & ((1 << hshift) - 1);
  int t = idx >> (6 + hshift);
  u16* p0 = X + (size_t)t * stride + h * D_ + i;
  float x1 = bf2f(p0[0]), x2 = bf2f(p0[64]);
  float fpos = (float)pos[t];
  float invf = exp2f(-(float)(2 * i) * (13.287712379549449f / 128.0f));
  float f = fpos * invf;
  float sv = __sinf(f), cv = __cosf(f);
  p0[0]  = f2bf(x1 * cv - x2 * sv);
  p0[64] = f2bf(x2 * cv + x1 * sv);
}

// ============ 256x256 8-phase GEMM (K=4096): C[M,N] = A[M,4096] @ Bt[N,4096]^T ============
// 8 waves (2Mx4N), BK=64, 128KB LDS dbuf, chunk-XOR swizzle, register fragment reuse
// (24 ds_read_b128/tile/wave), all-4-halves prefetch at distance 2 tiles, vmcnt(8)/tile.

#define SBAR() __builtin_amdgcn_sched_barrier(0)
#define BARX() do{ SBAR(); __builtin_amdgcn_s_barrier(); SBAR(); }while(0)

#define STG_A(PB, HALF, KT) do{ \
  gload_lds16(Ag + off0 + (size_t)(HALF)*1048576 + (size_t)(KT)*128, \
              (char*)smem + (PB)*32768 + (HALF)*16384 + w*1024); \
  gload_lds16(Ag + off0 + 524288 + (size_t)(HALF)*1048576 + (size_t)(KT)*128, \
              (char*)smem + (PB)*32768 + (HALF)*16384 + 8192 + w*1024); }while(0)
#define STG_B(PB, HALF, KT) do{ \
  gload_lds16(Bg + off0 + (size_t)(HALF)*1048576 + (size_t)(KT)*128, \
              (char*)smem + 65536 + (PB)*32768 + (HALF)*16384 + w*1024); \
  gload_lds16(Bg + off0 + 524288 + (size_t)(HALF)*1048576 + (size_t)(KT)*128, \
              (char*)smem + 65536 + (PB)*32768 + (HALF)*16384 + 8192 + w*1024); }while(0)

#define RD_A(DST, HALF) do{ \
  _Pragma("unroll") for (int ks = 0; ks < 2; ++ks) \
  _Pragma("unroll") for (int m = 0; m < 4; ++m) \
    DST[ks][m] = *(const bf16x8*)&smem[P*16384 + (HALF)*8192 + aRowBase + m*1024 + csw[ks]]; }while(0)
#define RD_B(DST, HALF) do{ \
  _Pragma("unroll") for (int ks = 0; ks < 2; ++ks) \
  _Pragma("unroll") for (int n = 0; n < 2; ++n) \
    DST[ks][n] = *(const bf16x8*)&smem[32768 + P*16384 + (HALF)*8192 + bRowBase + n*1024 + csw[ks]]; }while(0)

template<int MO, int NO>
__device__ __forceinline__ void mfma_quad(f32x4 (&acc)[8][4],
                                          const bf16x8 (&af)[2][4], const bf16x8 (&bf)[2][2]){
  __builtin_amdgcn_s_setprio(1);
  #pragma unroll
  for (int ks = 0; ks < 2; ++ks)
    #pragma unroll
    for (int m = 0; m < 4; ++m)
      #pragma unroll
      for (int n = 0; n < 2; ++n)
        acc[MO+m][NO+n] = __builtin_amdgcn_mfma_f32_16x16x32_bf16(af[ks][m], bf[ks][n], acc[MO+m][NO+n], 0, 0, 0);
  __builtin_amdgcn_s_setprio(0);
}

template<bool OUTF32>
__global__ __launch_bounds__(512, 2) void gemm256(const u16* __restrict__ A, const u16* __restrict__ Bt,
                                                  void* __restrict__ C, int Nn, int mt){
  __shared__ __align__(16) u16 smem[65536];   // 128 KB: As[2] bytes [0,65536), Bs[2] [65536,131072)
  const int tid = threadIdx.x;
  const int l = tid & 63, w = tid >> 6;
  const int lr = l & 15, lk = l >> 4;
  const int wr = w >> 2, wc = w & 3;

  // bijective XCD swizzle (nwg % 8 == 0 for both grids)
  const int nwg = gridDim.x;
  const int sbid = ((int)blockIdx.x & 7) * (nwg >> 3) + ((int)blockIdx.x >> 3);
  const int bx = sbid % mt, by = sbid / mt;
  const size_t arow0 = (size_t)bx * 256;
  const size_t brow0 = (size_t)by * 256;
  const char* Ag = (const char*)(A + arow0 * 4096);
  const char* Bg = (const char*)(Bt + brow0 * 4096);

  // per-thread staging source offset (row = w*8 + l/8, chunk = (l&7) ^ (row&7))
  const size_t off0 = (size_t)(w * 8 + (l >> 3)) * 8192 + (size_t)(((l & 7) ^ (l >> 3)) << 4);

  // ds_read bases (u16 units)
  const int aRowBase = (wr*64 + lr) * 64;
  const int bRowBase = (wc*32 + lr) * 64;
  int csw[2];
  csw[0] = ((lk     ) ^ (lr & 7)) << 3;
  csw[1] = ((lk + 4) ^ (lr & 7)) << 3;

  f32x4 acc[8][4];
  #pragma unroll
  for (int i = 0; i < 8; ++i)
    #pragma unroll
    for (int j = 0; j < 4; ++j){ acc[i][j][0]=0.f; acc[i][j][1]=0.f; acc[i][j][2]=0.f; acc[i][j][3]=0.f; }

  // prologue: stage tiles 0 and 1 completely (16 loads), drain tile 0
  STG_A(0, 0, 0); STG_B(0, 0, 0); STG_A(0, 1, 0); STG_B(0, 1, 0);
  STG_A(1, 0, 1); STG_B(1, 0, 1); STG_A(1, 1, 1); STG_B(1, 1, 1);
  asm volatile("s_waitcnt vmcnt(8)" ::: "memory");
  BARX();

  for (int t = 0; t < 64; ++t){
    const int P = t & 1;
    bf16x8 a0h[2][4], a1[2][4], b0[2][2], b1[2][2];
    // ---- ph1 (m0,n0): read A0 (held all tile) + B0 ----
    RD_A(a0h, 0); RD_B(b0, 0);
    BARX();
    mfma_quad<0,0>(acc, a0h, b0);
    BARX();
    // ---- ph2 (m1,n0): stage A0,B0[t+2]; read A1 ----
    if (t < 62){ STG_A(P, 0, t+2); STG_B(P, 0, t+2); }
    RD_A(a1, 1);
    BARX();
    mfma_quad<4,0>(acc, a1, b0);
    BARX();
    // ---- ph3 (m1,n1): stage A1[t+2]; read B1 ----
    if (t < 62){ STG_A(P, 1, t+2); }
    RD_B(b1, 1);
    BARX();
    mfma_quad<4,2>(acc, a1, b1);
    BARX();
    // ---- ph4 (m0,n1): stage B1[t+2]; reuse held A0 ----
    if (t < 62){ STG_B(P, 1, t+2); }
    BARX();
    mfma_quad<0,2>(acc, a0h, b1);
    if (t < 62)      asm volatile("s_waitcnt vmcnt(8)" ::: "memory");
    else if (t < 63) asm volatile("s_waitcnt vmcnt(0)" ::: "memory");
    BARX();
  }

  // epilogue: C row = ... + lk*4 + j, col = ... + lr  [m89 layout]
  #pragma unroll
  for (int mh = 0; mh < 2; ++mh)
    #pragma unroll
    for (int m = 0; m < 4; ++m)
      #pragma unroll
      for (int nh = 0; nh < 2; ++nh)
        #pragma unroll
        for (int n = 0; n < 2; ++n)
          #pragma unroll
          for (int j = 0; j < 4; ++j){
            size_t gr = arow0 + mh*128 + wr*64 + m*16 + lk*4 + j;
            size_t gc = brow0 + nh*128 + wc*32 + n*16 + lr;
            float v = acc[mh*4+m][nh*2+n][j];
            if (OUTF32) ((float*)C)[gr * Nn + gc] = v;
            else        ((u16*)C)[gr * Nn + gc] = f2bf(v);
          }
}

// ---------------- flash attention: 8 waves x 32 q-rows, KVBLK=64, 32x32x16 MFMA ----------------
__global__ __launch_bounds__(512, 2) void attn_k(const u16* __restrict__ QKV,
                                                 const u16* __restrict__ Vtg,
                                                 u16* __restrict__ ctx){
  __shared__ __align__(16) u16 smem[32768];   // 64 KB
  const int tid = threadIdx.x;
  const int l = tid & 63, w = tid >> 6;
  const int lane31 = l & 31, hi = l >> 5;
  const int hb = blockIdx.x;
  const int b = hb >> 5, h = hb & 31, kvh = h >> 2;
  const int qb = 7 - blockIdx.y;              // LPT
  const int q0w = qb * 256 + w * 32;
  const int qg = q0w + lane31;

  const u16* Qp = QKV + (size_t)b * S_ * QSTR + (size_t)h * D_;
  const char* Kp = (const char*)(QKV + (size_t)b * S_ * QSTR + 4096 + (size_t)kvh * D_);
  const char* Vp = (const char*)(Vtg + ((size_t)b * 1024 + kvh * 128) * S_);

  bf16x8 qf[8];
  #pragma unroll
  for (int dt = 0; dt < 8; ++dt)
    qf[dt] = *(const bf16x8*)(Qp + (size_t)qg * QSTR + dt * 16 + hi * 8);

  const int krow0 = (2*w)*4 + (l >> 4), krow1 = krow0 + 4;
  const size_t koff0 = (size_t)krow0 * (QSTR*2) + (((l & 15) << 4) ^ ((krow0 & 7) << 4));
  const size_t koff1 = (size_t)krow1 * (QSTR*2) + (((l & 15) << 4) ^ ((krow1 & 7) << 4));
  const int vrow0 = (2*w)*8 + (l >> 3), vrow1 = vrow0 + 8;
  const size_t voff0 = (size_t)vrow0 * (S_*2) + (((l & 7) << 4) ^ ((vrow0 & 7) << 4));
  const size_t voff1 = (size_t)vrow1 * (S_*2) + (((l & 7) << 4) ^ ((vrow1 & 7) << 4));

  f32x16 acc[4];
  #pragma unroll
  for (int dt = 0; dt < 4; ++dt)
    #pragma unroll
    for (int i = 0; i < 16; ++i) acc[dt][i] = 0.f;
  float mrow = -3e38f, lsum = 0.f;

  const int nt = qb * 4 + 4;

  auto STAGE = [&](int t, int bufn){
    char* Kb = (char*)smem + bufn * 16384;
    char* Vb = (char*)smem + 32768 + bufn * 16384;
    size_t kb = (size_t)t * 64 * (QSTR*2);
    size_t vb = (size_t)t * 128;
    gload_lds16(Kp + kb + koff0, Kb + (2*w)*1024);
    gload_lds16(Kp + kb + koff1, Kb + (2*w+1)*1024);
    gload_lds16(Vp + vb + voff0, Vb + (2*w)*1024);
    gload_lds16(Vp + vb + voff1, Vb + (2*w+1)*1024);
  };

  STAGE(0, 0);
  __syncthreads();
  int buf = 0;
  for (int t = 0; t < nt; ++t){
    if (t + 1 < nt) STAGE(t + 1, buf ^ 1);
    const int kbase = t * 64;
    if (kbase <= q0w + 31){
      const char* Kb = (const char*)smem + buf * 16384;
      const char* Vb = (const char*)smem + 32768 + buf * 16384;
      const int swz = (lane31 & 7) << 4;

      f32x16 s0, s1;
      #pragma unroll
      for (int i = 0; i < 16; ++i){ s0[i] = 0.f; s1[i] = 0.f; }
      #pragma unroll
      for (int dt = 0; dt < 8; ++dt){
        bf16x8 kf = *(const bf16x8*)(Kb + lane31*256 + ((dt*32 + hi*16) ^ swz));
        s0 = __builtin_amdgcn_mfma_f32_32x32x16_bf16(kf, qf[dt], s0, 0, 0, 0);
      }
      #pragma unroll
      for (int dt = 0; dt < 8; ++dt){
        bf16x8 kf = *(const bf16x8*)(Kb + (32 + lane31)*256 + ((dt*32 + hi*16) ^ swz));
        s1 = __builtin_amdgcn_mfma_f32_32x32x16_bf16(kf, qf[dt], s1, 0, 0, 0);
      }

      if (kbase + 63 > q0w){
        int thr = qg - kbase;
        #pragma unroll
        for (int r = 0; r < 16; ++r){
          int kc = (r & 3) + 8*(r >> 2) + 4*hi;
          s0[r] = (kc > thr)      ? -1e30f : s0[r];
          s1[r] = (kc + 32 > thr) ? -1e30f : s1[r];
        }
      }

      float tmax = s0[0];
      #pragma unroll
      for (int r = 1; r < 16; ++r) tmax = fmaxf(tmax, s0[r]);
      #pragma unroll
      for (int r = 0; r < 16; ++r) tmax = fmaxf(tmax, s1[r]);
      tmax = fmaxf(tmax, __shfl_xor(tmax, 32));
      float mn = fmaxf(mrow, tmax);
      float rf = exp2f((mrow - mn) * KSC);
      mrow = mn;
      float ps = 0.f;
      #pragma unroll
      for (int r = 0; r < 16; ++r){
        float a = exp2f((s0[r] - mn) * KSC);
        float c = exp2f((s1[r] - mn) * KSC);
        s0[r] = a; s1[r] = c; ps += a + c;
      }
      ps += __shfl_xor(ps, 32);
      lsum = lsum * rf + ps;
      #pragma unroll
      for (int dt = 0; dt < 4; ++dt)
        #pragma unroll
        for (int i = 0; i < 16; ++i) acc[dt][i] *= rf;

      u32 pw[16];
      #pragma unroll
      for (int g = 0; g < 4; ++g){
        pw[2*g]     = (u32)f2bf(s0[4*g])   | ((u32)f2bf(s0[4*g+1]) << 16);
        pw[2*g+1]   = (u32)f2bf(s0[4*g+2]) | ((u32)f2bf(s0[4*g+3]) << 16);
        pw[8+2*g]   = (u32)f2bf(s1[4*g])   | ((u32)f2bf(s1[4*g+1]) << 16);
        pw[8+2*g+1] = (u32)f2bf(s1[4*g+2]) | ((u32)f2bf(s1[4*g+3]) << 16);
      }

      #pragma unroll
      for (int kt = 0; kt < 4; ++kt){
        u32 W0 = pw[kt*4+0], W1 = pw[kt*4+1], W2 = pw[kt*4+2], W3 = pw[kt*4+3];
        u32 x0 = hi ? W0 : W2;
        u32 x1 = hi ? W1 : W3;
        u32 y0 = __shfl_xor(x0, 32);
        u32 y1 = __shfl_xor(x1, 32);
        u32 w0 = hi ? y0 : W0;
        u32 w1 = hi ? y1 : W1;
        u32 w2 = hi ? W2 : y0;
        u32 w3 = hi ? W3 : y1;
        u32x4 pk; pk[0]=w0; pk[1]=w1; pk[2]=w2; pk[3]=w3;
        bf16x8 pa = __builtin_bit_cast(bf16x8, pk);
        #pragma unroll
        for (int dt = 0; dt < 4; ++dt){
          bf16x8 vf = *(const bf16x8*)(Vb + (dt*32 + lane31)*128 + ((kt*32 + hi*16) ^ swz));
          acc[dt] = __builtin_amdgcn_mfma_f32_32x32x16_bf16(vf, pa, acc[dt], 0, 0, 0);
        }
      }
    }
    __syncthreads();
    buf ^= 1;
  }

  __syncthreads();
  u16* Ot = smem + w * 4096;
  float inv = 1.f / lsum;
  #pragma unroll
  for (int dt = 0; dt < 4; ++dt)
    #pragma unroll
    for (int r = 0; r < 16; ++r){
      int d = dt*32 + (r & 3) + 8*(r >> 2) + 4*hi;
      Ot[lane31*128 + (d ^ ((lane31 & 15) << 2))] = f2bf(acc[dt][r] * inv);
    }
  u16* outp = ctx + ((size_t)(b * S_ + q0w)) * HID_ + h * D_;
  #pragma unroll
  for (int it = 0; it < 16; ++it){
    int id = it * 64 + l;
    int q = id >> 5;
    int c4 = (id & 31) * 4;
    ushort4 vv = *(const ushort4*)(Ot + q*128 + (c4 ^ ((q & 15) << 2)));
    *(ushort4*)(outp + (size_t)q * HID_ + c4) = vv;
  }
}

extern "C" void kernel_launch(void* const* d_in, const int* in_sizes, int n_in,
                              void* d_out, int out_size, void* d_ws, size_t ws_size,
                              hipStream_t stream) {
  const float* x  = (const float*)d_in[0];
  const int*   pos = (const int*)d_in[2];
  const float* Wq = (const float*)d_in[3];
  const float* Wk = (const float*)d_in[4];
  const float* Wv = (const float*)d_in[5];
  const float* Wo = (const float*)d_in[6];

  char* ws = (char*)d_ws;
  u16* xb   = (u16*)(ws);                               // 32MB; reused as ctx after QKV
  u16* WT   = (u16*)(ws + ((size_t)32 << 20));          // 48MB: Wq^T|Wk^T|Wv^T (dead after QKV gemm)
  u16* WoT  = (u16*)(ws + ((size_t)80 << 20));          // 32MB
  u16* QKVb = (u16*)(ws + ((size_t)112 << 20));         // 48MB: [4096][6144]
  u16* Vtg  = (u16*)(ws + ((size_t)32 << 20));          // 8MB overlay on WT: [b*1024+vd][S]

  cast_f32_bf16<<<16384, 256, 0, stream>>>(x, xb, HID_ * M_);
  tcast<<<dim3(64, 64), 256, 0, stream>>>(Wq, WT, 4096, 4096);
  tcast<<<dim3(64, 16), 256, 0, stream>>>(Wk, WT + (size_t)4096 * 4096, 4096, 1024);
  tcast<<<dim3(64, 16), 256, 0, stream>>>(Wv, WT + (size_t)5120 * 4096, 4096, 1024);
  tcast<<<dim3(64, 64), 256, 0, stream>>>(Wo, WoT, 4096, 4096);
  gemm256<false><<<16 * 24, 512, 0, stream>>>(xb, WT, QKVb, 6144, 16);
  rope_k<<<32768, 256, 0, stream>>>(QKVb,        pos, 5, QSTR);
  rope_k<<<8192,  256, 0, stream>>>(QKVb + 4096, pos, 3, QSTR);
  vtrans<<<dim3(32, 32), 256, 0, stream>>>(QKVb, Vtg);
  attn_k<<<dim3(64, 8), 512, 0, stream>>>(QKVb, Vtg, xb);
  gemm256<true><<<16 * 16, 512, 0, stream>>>(xb, WoT, d_out, 4096, 16);
}

// Round 5
// 545.085 us; speedup vs baseline: 2.5951x; 1.0033x over previous
//
#include <hip/hip_runtime.h>
#include <cstdint>
#include <cstddef>

#define B_   2
#define S_   2048
#define HID_ 4096
#define H_   32
#define KV_  8
#define D_   128
#define M_   (B_*S_)      // 4096 tokens
#define QSTR 6144         // QKV combined row stride (H*D + 2*KV*D)

typedef __attribute__((ext_vector_type(8))) short bf16x8;
typedef __attribute__((ext_vector_type(4))) float f32x4;
typedef __attribute__((ext_vector_type(16))) float f32x16;
typedef __attribute__((ext_vector_type(4))) unsigned int u32x4;
typedef unsigned short u16;
typedef unsigned int   u32;

// softmax scale folded into exp2: SCALE * log2(e)
#define KSC (0.08838834764831845f * 1.4426950408889634f)

__device__ __forceinline__ float bf2f(u16 v){ u32 u = ((u32)v) << 16; return __builtin_bit_cast(float, u); }
__device__ __forceinline__ u16 f2bf(float f){
  u32 u = __builtin_bit_cast(u32, f);
  u32 r = u + 0x7fffu + ((u >> 16) & 1u);   // RNE
  return (u16)(r >> 16);
}

__device__ __forceinline__ void gload_lds16(const void* g, void* lds){
  __builtin_amdgcn_global_load_lds(
      (const __attribute__((address_space(1))) void*)g,
      (__attribute__((address_space(3))) void*)lds, 16, 0, 0);
}

// ---------------- cast fp32 -> bf16 (vectorized) ----------------
__global__ void cast_f32_bf16(const float* __restrict__ in, u16* __restrict__ out, int n){
  int i = (blockIdx.x * blockDim.x + threadIdx.x) * 4;
  if (i >= n) return;
  float4 v = *(const float4*)(in + i);
  ushort4 o;
  o.x = f2bf(v.x); o.y = f2bf(v.y); o.z = f2bf(v.z); o.w = f2bf(v.w);
  *(ushort4*)(out + i) = o;
}

// ---------------- transpose-cast: W[Kd][Nd] fp32 -> WT[Nd][Kd] bf16 ----------------
__global__ __launch_bounds__(256) void tcast(const float* __restrict__ W, u16* __restrict__ WT,
                                             int Kd, int Nd){
  __shared__ __align__(16) u16 t[64][65];     // t[n][k]
  int k0 = blockIdx.x * 64, n0 = blockIdx.y * 64;
  int lx = threadIdx.x & 15, ly = threadIdx.x >> 4;
  #pragma unroll
  for (int rr = 0; rr < 4; ++rr){
    int r = rr * 16 + ly;                     // k-row in tile
    float4 v = *(const float4*)(W + (size_t)(k0 + r) * Nd + n0 + lx * 4);
    t[lx*4+0][r] = f2bf(v.x);
    t[lx*4+1][r] = f2bf(v.y);
    t[lx*4+2][r] = f2bf(v.z);
    t[lx*4+3][r] = f2bf(v.w);
  }
  __syncthreads();
  #pragma unroll
  for (int rr = 0; rr < 4; ++rr){
    int r = rr * 16 + ly;                     // n-row in tile
    ushort4 o;
    o.x = t[r][lx*4+0]; o.y = t[r][lx*4+1]; o.z = t[r][lx*4+2]; o.w = t[r][lx*4+3];
    *(ushort4*)(WT + (size_t)(n0 + r) * Kd + k0 + lx * 4) = o;
  }
}

// ---------------- transpose V (bf16): QKV[t][5120 + vd] -> Vt[b*1024+vd][s] ----------------
__global__ __launch_bounds__(256) void vtrans(const u16* __restrict__ QKV, u16* __restrict__ Vt){
  __shared__ __align__(16) u16 t[64][65];
  int stile = blockIdx.x;                 // 0..31
  int b = blockIdx.y >> 4, vt = blockIdx.y & 15;
  int s0 = stile * 64, c0 = vt * 64;
  int lx = threadIdx.x & 15, ly = threadIdx.x >> 4;
  #pragma unroll
  for (int rr = 0; rr < 4; ++rr){
    int r = rr * 16 + ly;                 // s-row
    ushort4 v = *(const ushort4*)(QKV + (size_t)(b*S_ + s0 + r) * QSTR + 5120 + c0 + lx*4);
    t[lx*4+0][r]=v.x; t[lx*4+1][r]=v.y; t[lx*4+2][r]=v.z; t[lx*4+3][r]=v.w;
  }
  __syncthreads();
  #pragma unroll
  for (int rr = 0; rr < 4; ++rr){
    int r = rr * 16 + ly;                 // vd-row
    ushort4 o;
    o.x=t[r][lx*4+0]; o.y=t[r][lx*4+1]; o.z=t[r][lx*4+2]; o.w=t[r][lx*4+3];
    *(ushort4*)(Vt + (size_t)(b*1024 + c0 + r) * S_ + s0 + lx*4) = o;
  }
}

// ---------------- RoPE in-place on bf16 [M_][stride] rows ----------------
__global__ void rope_k(u16* __restrict__ X, const int* __restrict__ pos, int hshift, int stride){
  int idx = blockIdx.x * 256 + threadIdx.x;
  int i = idx & 63;
  int h = (idx >> 6) & ((1 << hshift) - 1);
  int t = idx >> (6 + hshift);
  u16* p0 = X + (size_t)t * stride + h * D_ + i;
  float x1 = bf2f(p0[0]), x2 = bf2f(p0[64]);
  float fpos = (float)pos[t];
  float invf = exp2f(-(float)(2 * i) * (13.287712379549449f / 128.0f));
  float f = fpos * invf;
  float sv = __sinf(f), cv = __cosf(f);
  p0[0]  = f2bf(x1 * cv - x2 * sv);
  p0[64] = f2bf(x2 * cv + x1 * sv);
}

// ============ 256x256 8-phase GEMM (K=4096): C[M,N] = A[M,4096] @ Bt[N,4096]^T ============
// 8 waves (2Mx4N), BK=64, 128KB LDS dbuf, chunk-XOR swizzle, ONE-PHASE-AHEAD fragment reads
// (every ds_read has >=1 barrier-pair of slack before its consuming MFMA), staging at
// ph2/ph3/ph4 into just-freed halves, vmcnt(6) at ph3.  WAR audit per half:
//  A0/B0[P] read prev-ph4, drained by ph1 MFMA lgkm+bar -> staged ph2.
//  A1[P] read ph1, drained by ph2 MFMA lgkm+bar -> staged ph3.
//  B1[P] read ph2, drained by ph3 MFMA lgkm+bar -> staged ph4.
//  ph4 reads next tile's A0/B0[P^1] after vmcnt(6)+bar guaranteed residency.

#define SBAR() __builtin_amdgcn_sched_barrier(0)
#define BARX() do{ SBAR(); __builtin_amdgcn_s_barrier(); SBAR(); }while(0)

#define STG_A(PB, HALF, KT) do{ \
  gload_lds16(Ag + off0 + (size_t)(HALF)*1048576 + (size_t)(KT)*128, \
              (char*)smem + (PB)*32768 + (HALF)*16384 + w*1024); \
  gload_lds16(Ag + off0 + 524288 + (size_t)(HALF)*1048576 + (size_t)(KT)*128, \
              (char*)smem + (PB)*32768 + (HALF)*16384 + 8192 + w*1024); }while(0)
#define STG_B(PB, HALF, KT) do{ \
  gload_lds16(Bg + off0 + (size_t)(HALF)*1048576 + (size_t)(KT)*128, \
              (char*)smem + 65536 + (PB)*32768 + (HALF)*16384 + w*1024); \
  gload_lds16(Bg + off0 + 524288 + (size_t)(HALF)*1048576 + (size_t)(KT)*128, \
              (char*)smem + 65536 + (PB)*32768 + (HALF)*16384 + 8192 + w*1024); }while(0)

#define RD_A(DST, PP, HALF) do{ \
  _Pragma("unroll") for (int ks = 0; ks < 2; ++ks) \
  _Pragma("unroll") for (int m = 0; m < 4; ++m) \
    DST[ks][m] = *(const bf16x8*)&smem[(PP)*16384 + (HALF)*8192 + aRowBase + m*1024 + csw[ks]]; }while(0)
#define RD_B(DST, PP, HALF) do{ \
  _Pragma("unroll") for (int ks = 0; ks < 2; ++ks) \
  _Pragma("unroll") for (int n = 0; n < 2; ++n) \
    DST[ks][n] = *(const bf16x8*)&smem[32768 + (PP)*16384 + (HALF)*8192 + bRowBase + n*1024 + csw[ks]]; }while(0)

template<int MO, int NO>
__device__ __forceinline__ void mfma_quad(f32x4 (&acc)[8][4],
                                          const bf16x8 (&af)[2][4], const bf16x8 (&bf)[2][2]){
  __builtin_amdgcn_s_setprio(1);
  #pragma unroll
  for (int ks = 0; ks < 2; ++ks)
    #pragma unroll
    for (int m = 0; m < 4; ++m)
      #pragma unroll
      for (int n = 0; n < 2; ++n)
        acc[MO+m][NO+n] = __builtin_amdgcn_mfma_f32_16x16x32_bf16(af[ks][m], bf[ks][n], acc[MO+m][NO+n], 0, 0, 0);
  __builtin_amdgcn_s_setprio(0);
}

template<bool OUTF32>
__global__ __launch_bounds__(512, 2) void gemm256(const u16* __restrict__ A, const u16* __restrict__ Bt,
                                                  void* __restrict__ C, int Nn, int mt){
  __shared__ __align__(16) u16 smem[65536];   // 128 KB: As[2] bytes [0,65536), Bs[2] [65536,131072)
  const int tid = threadIdx.x;
  const int l = tid & 63, w = tid >> 6;
  const int lr = l & 15, lk = l >> 4;
  const int wr = w >> 2, wc = w & 3;

  // bijective XCD swizzle (nwg % 8 == 0 for both grids)
  const int nwg = gridDim.x;
  const int sbid = ((int)blockIdx.x & 7) * (nwg >> 3) + ((int)blockIdx.x >> 3);
  const int bx = sbid % mt, by = sbid / mt;
  const size_t arow0 = (size_t)bx * 256;
  const size_t brow0 = (size_t)by * 256;
  const char* Ag = (const char*)(A + arow0 * 4096);
  const char* Bg = (const char*)(Bt + brow0 * 4096);

  // per-thread staging source offset (row = w*8 + l/8, chunk = (l&7) ^ (row&7))
  const size_t off0 = (size_t)(w * 8 + (l >> 3)) * 8192 + (size_t)(((l & 7) ^ (l >> 3)) << 4);

  // ds_read bases (u16 units)
  const int aRowBase = (wr*64 + lr) * 64;
  const int bRowBase = (wc*32 + lr) * 64;
  int csw[2];
  csw[0] = ((lk     ) ^ (lr & 7)) << 3;
  csw[1] = ((lk + 4) ^ (lr & 7)) << 3;

  f32x4 acc[8][4];
  #pragma unroll
  for (int i = 0; i < 8; ++i)
    #pragma unroll
    for (int j = 0; j < 4; ++j){ acc[i][j][0]=0.f; acc[i][j][1]=0.f; acc[i][j][2]=0.f; acc[i][j][3]=0.f; }

  // prologue: stage tiles 0 and 1 completely (16 loads/wave), drain tile 0, preload A0/B0 frags
  STG_A(0, 0, 0); STG_B(0, 0, 0); STG_A(0, 1, 0); STG_B(0, 1, 0);
  STG_A(1, 0, 1); STG_B(1, 0, 1); STG_A(1, 1, 1); STG_B(1, 1, 1);
  asm volatile("s_waitcnt vmcnt(8)" ::: "memory");
  BARX();
  bf16x8 a0c[2][4], b0c[2][2], a1f[2][4], b1f[2][2];
  RD_A(a0c, 0, 0); RD_B(b0c, 0, 0);

  for (int t = 0; t < 64; ++t){
    const int P = t & 1;
    // ---- ph1: read A1[t] (used ph2); MFMA m0n0 on held A0/B0 ----
    RD_A(a1f, P, 1);
    BARX();
    mfma_quad<0,0>(acc, a0c, b0c);
    BARX();
    // ---- ph2: stage A0,B0[t+2] (halves freed by ph1); read B1[t] (used ph3); MFMA m1n0 ----
    if (t < 62){ STG_A(P, 0, t+2); STG_B(P, 0, t+2); }
    RD_B(b1f, P, 1);
    BARX();
    mfma_quad<4,0>(acc, a1f, b0c);
    BARX();
    // ---- ph3: stage A1[t+2]; vmcnt(6) forces tile t+1 resident; MFMA m1n1 ----
    if (t < 62){
      STG_A(P, 1, t+2);
      asm volatile("s_waitcnt vmcnt(6)" ::: "memory");
    } else if (t == 62){
      asm volatile("s_waitcnt vmcnt(0)" ::: "memory");
    }
    BARX();
    mfma_quad<4,2>(acc, a1f, b1f);
    BARX();
    // ---- ph4: stage B1[t+2]; MFMA m0n1; then refill A0/B0 regs from tile t+1 (in place) ----
    if (t < 62){ STG_B(P, 1, t+2); }
    BARX();
    mfma_quad<0,2>(acc, a0c, b1f);
    SBAR();   // pin: refill reads must stay AFTER the MFMA cluster (in-place reg reuse)
    if (t < 63){ RD_A(a0c, P^1, 0); RD_B(b0c, P^1, 0); }
    BARX();
  }

  // epilogue: C row = ... + lk*4 + j, col = ... + lr  [m89 layout]
  #pragma unroll
  for (int mh = 0; mh < 2; ++mh)
    #pragma unroll
    for (int m = 0; m < 4; ++m)
      #pragma unroll
      for (int nh = 0; nh < 2; ++nh)
        #pragma unroll
        for (int n = 0; n < 2; ++n)
          #pragma unroll
          for (int j = 0; j < 4; ++j){
            size_t gr = arow0 + mh*128 + wr*64 + m*16 + lk*4 + j;
            size_t gc = brow0 + nh*128 + wc*32 + n*16 + lr;
            float v = acc[mh*4+m][nh*2+n][j];
            if (OUTF32) ((float*)C)[gr * Nn + gc] = v;
            else        ((u16*)C)[gr * Nn + gc] = f2bf(v);
          }
}

// ---------------- flash attention: 8 waves x 32 q-rows, KVBLK=64, 32x32x16 MFMA ----------------
__global__ __launch_bounds__(512, 2) void attn_k(const u16* __restrict__ QKV,
                                                 const u16* __restrict__ Vtg,
                                                 u16* __restrict__ ctx){
  __shared__ __align__(16) u16 smem[32768];   // 64 KB
  const int tid = threadIdx.x;
  const int l = tid & 63, w = tid >> 6;
  const int lane31 = l & 31, hi = l >> 5;
  const int hb = blockIdx.x;
  const int b = hb >> 5, h = hb & 31, kvh = h >> 2;
  const int qb = 7 - blockIdx.y;              // LPT
  const int q0w = qb * 256 + w * 32;
  const int qg = q0w + lane31;

  const u16* Qp = QKV + (size_t)b * S_ * QSTR + (size_t)h * D_;
  const char* Kp = (const char*)(QKV + (size_t)b * S_ * QSTR + 4096 + (size_t)kvh * D_);
  const char* Vp = (const char*)(Vtg + ((size_t)b * 1024 + kvh * 128) * S_);

  bf16x8 qf[8];
  #pragma unroll
  for (int dt = 0; dt < 8; ++dt)
    qf[dt] = *(const bf16x8*)(Qp + (size_t)qg * QSTR + dt * 16 + hi * 8);

  const int krow0 = (2*w)*4 + (l >> 4), krow1 = krow0 + 4;
  const size_t koff0 = (size_t)krow0 * (QSTR*2) + (((l & 15) << 4) ^ ((krow0 & 7) << 4));
  const size_t koff1 = (size_t)krow1 * (QSTR*2) + (((l & 15) << 4) ^ ((krow1 & 7) << 4));
  const int vrow0 = (2*w)*8 + (l >> 3), vrow1 = vrow0 + 8;
  const size_t voff0 = (size_t)vrow0 * (S_*2) + (((l & 7) << 4) ^ ((vrow0 & 7) << 4));
  const size_t voff1 = (size_t)vrow1 * (S_*2) + (((l & 7) << 4) ^ ((vrow1 & 7) << 4));

  f32x16 acc[4];
  #pragma unroll
  for (int dt = 0; dt < 4; ++dt)
    #pragma unroll
    for (int i = 0; i < 16; ++i) acc[dt][i] = 0.f;
  float mrow = -3e38f, lsum = 0.f;

  const int nt = qb * 4 + 4;

  auto STAGE = [&](int t, int bufn){
    char* Kb = (char*)smem + bufn * 16384;
    char* Vb = (char*)smem + 32768 + bufn * 16384;
    size_t kb = (size_t)t * 64 * (QSTR*2);
    size_t vb = (size_t)t * 128;
    gload_lds16(Kp + kb + koff0, Kb + (2*w)*1024);
    gload_lds16(Kp + kb + koff1, Kb + (2*w+1)*1024);
    gload_lds16(Vp + vb + voff0, Vb + (2*w)*1024);
    gload_lds16(Vp + vb + voff1, Vb + (2*w+1)*1024);
  };

  STAGE(0, 0);
  __syncthreads();
  int buf = 0;
  for (int t = 0; t < nt; ++t){
    if (t + 1 < nt) STAGE(t + 1, buf ^ 1);
    const int kbase = t * 64;
    if (kbase <= q0w + 31){
      const char* Kb = (const char*)smem + buf * 16384;
      const char* Vb = (const char*)smem + 32768 + buf * 16384;
      const int swz = (lane31 & 7) << 4;

      f32x16 s0, s1;
      #pragma unroll
      for (int i = 0; i < 16; ++i){ s0[i] = 0.f; s1[i] = 0.f; }
      #pragma unroll
      for (int dt = 0; dt < 8; ++dt){
        bf16x8 kf = *(const bf16x8*)(Kb + lane31*256 + ((dt*32 + hi*16) ^ swz));
        s0 = __builtin_amdgcn_mfma_f32_32x32x16_bf16(kf, qf[dt], s0, 0, 0, 0);
      }
      #pragma unroll
      for (int dt = 0; dt < 8; ++dt){
        bf16x8 kf = *(const bf16x8*)(Kb + (32 + lane31)*256 + ((dt*32 + hi*16) ^ swz));
        s1 = __builtin_amdgcn_mfma_f32_32x32x16_bf16(kf, qf[dt], s1, 0, 0, 0);
      }

      if (kbase + 63 > q0w){
        int thr = qg - kbase;
        #pragma unroll
        for (int r = 0; r < 16; ++r){
          int kc = (r & 3) + 8*(r >> 2) + 4*hi;
          s0[r] = (kc > thr)      ? -1e30f : s0[r];
          s1[r] = (kc + 32 > thr) ? -1e30f : s1[r];
        }
      }

      float tmax = s0[0];
      #pragma unroll
      for (int r = 1; r < 16; ++r) tmax = fmaxf(tmax, s0[r]);
      #pragma unroll
      for (int r = 0; r < 16; ++r) tmax = fmaxf(tmax, s1[r]);
      tmax = fmaxf(tmax, __shfl_xor(tmax, 32));
      float mn = fmaxf(mrow, tmax);
      float rf = exp2f((mrow - mn) * KSC);
      mrow = mn;
      float ps = 0.f;
      #pragma unroll
      for (int r = 0; r < 16; ++r){
        float a = exp2f((s0[r] - mn) * KSC);
        float c = exp2f((s1[r] - mn) * KSC);
        s0[r] = a; s1[r] = c; ps += a + c;
      }
      ps += __shfl_xor(ps, 32);
      lsum = lsum * rf + ps;
      #pragma unroll
      for (int dt = 0; dt < 4; ++dt)
        #pragma unroll
        for (int i = 0; i < 16; ++i) acc[dt][i] *= rf;

      u32 pw[16];
      #pragma unroll
      for (int g = 0; g < 4; ++g){
        pw[2*g]     = (u32)f2bf(s0[4*g])   | ((u32)f2bf(s0[4*g+1]) << 16);
        pw[2*g+1]   = (u32)f2bf(s0[4*g+2]) | ((u32)f2bf(s0[4*g+3]) << 16);
        pw[8+2*g]   = (u32)f2bf(s1[4*g])   | ((u32)f2bf(s1[4*g+1]) << 16);
        pw[8+2*g+1] = (u32)f2bf(s1[4*g+2]) | ((u32)f2bf(s1[4*g+3]) << 16);
      }

      #pragma unroll
      for (int kt = 0; kt < 4; ++kt){
        u32 W0 = pw[kt*4+0], W1 = pw[kt*4+1], W2 = pw[kt*4+2], W3 = pw[kt*4+3];
        u32 x0 = hi ? W0 : W2;
        u32 x1 = hi ? W1 : W3;
        u32 y0 = __shfl_xor(x0, 32);
        u32 y1 = __shfl_xor(x1, 32);
        u32 w0 = hi ? y0 : W0;
        u32 w1 = hi ? y1 : W1;
        u32 w2 = hi ? W2 : y0;
        u32 w3 = hi ? W3 : y1;
        u32x4 pk; pk[0]=w0; pk[1]=w1; pk[2]=w2; pk[3]=w3;
        bf16x8 pa = __builtin_bit_cast(bf16x8, pk);
        #pragma unroll
        for (int dt = 0; dt < 4; ++dt){
          bf16x8 vf = *(const bf16x8*)(Vb + (dt*32 + lane31)*128 + ((kt*32 + hi*16) ^ swz));
          acc[dt] = __builtin_amdgcn_mfma_f32_32x32x16_bf16(vf, pa, acc[dt], 0, 0, 0);
        }
      }
    }
    __syncthreads();
    buf ^= 1;
  }

  __syncthreads();
  u16* Ot = smem + w * 4096;
  float inv = 1.f / lsum;
  #pragma unroll
  for (int dt = 0; dt < 4; ++dt)
    #pragma unroll
    for (int r = 0; r < 16; ++r){
      int d = dt*32 + (r & 3) + 8*(r >> 2) + 4*hi;
      Ot[lane31*128 + (d ^ ((lane31 & 15) << 2))] = f2bf(acc[dt][r] * inv);
    }
  u16* outp = ctx + ((size_t)(b * S_ + q0w)) * HID_ + h * D_;
  #pragma unroll
  for (int it = 0; it < 16; ++it){
    int id = it * 64 + l;
    int q = id >> 5;
    int c4 = (id & 31) * 4;
    ushort4 vv = *(const ushort4*)(Ot + q*128 + (c4 ^ ((q & 15) << 2)));
    *(ushort4*)(outp + (size_t)q * HID_ + c4) = vv;
  }
}

extern "C" void kernel_launch(void* const* d_in, const int* in_sizes, int n_in,
                              void* d_out, int out_size, void* d_ws, size_t ws_size,
                              hipStream_t stream) {
  const float* x  = (const float*)d_in[0];
  const int*   pos = (const int*)d_in[2];
  const float* Wq = (const float*)d_in[3];
  const float* Wk = (const float*)d_in[4];
  const float* Wv = (const float*)d_in[5];
  const float* Wo = (const float*)d_in[6];

  char* ws = (char*)d_ws;
  u16* xb   = (u16*)(ws);                               // 32MB; reused as ctx after QKV
  u16* WT   = (u16*)(ws + ((size_t)32 << 20));          // 48MB: Wq^T|Wk^T|Wv^T (dead after QKV gemm)
  u16* WoT  = (u16*)(ws + ((size_t)80 << 20));          // 32MB
  u16* QKVb = (u16*)(ws + ((size_t)112 << 20));         // 48MB: [4096][6144]
  u16* Vtg  = (u16*)(ws + ((size_t)32 << 20));          // 8MB overlay on WT: [b*1024+vd][S]

  cast_f32_bf16<<<16384, 256, 0, stream>>>(x, xb, HID_ * M_);
  tcast<<<dim3(64, 64), 256, 0, stream>>>(Wq, WT, 4096, 4096);
  tcast<<<dim3(64, 16), 256, 0, stream>>>(Wk, WT + (size_t)4096 * 4096, 4096, 1024);
  tcast<<<dim3(64, 16), 256, 0, stream>>>(Wv, WT + (size_t)5120 * 4096, 4096, 1024);
  tcast<<<dim3(64, 64), 256, 0, stream>>>(Wo, WoT, 4096, 4096);
  gemm256<false><<<16 * 24, 512, 0, stream>>>(xb, WT, QKVb, 6144, 16);
  rope_k<<<32768, 256, 0, stream>>>(QKVb,        pos, 5, QSTR);
  rope_k<<<8192,  256, 0, stream>>>(QKVb + 4096, pos, 3, QSTR);
  vtrans<<<dim3(32, 32), 256, 0, stream>>>(QKVb, Vtg);
  attn_k<<<dim3(64, 8), 512, 0, stream>>>(QKVb, Vtg, xb);
  gemm256<true><<<16 * 16, 512, 0, stream>>>(xb, WoT, d_out, 4096, 16);
}

// Round 6
// 542.108 us; speedup vs baseline: 2.6094x; 1.0055x over previous
//
#include <hip/hip_runtime.h>
#include <cstdint>
#include <cstddef>

#define B_   2
#define S_   2048
#define HID_ 4096
#define H_   32
#define KV_  8
#define D_   128
#define M_   (B_*S_)      // 4096 tokens
#define QSTR 6144         // QKV combined row stride (H*D + 2*KV*D)

typedef __attribute__((ext_vector_type(8))) short bf16x8;
typedef __attribute__((ext_vector_type(4))) float f32x4;
typedef __attribute__((ext_vector_type(16))) float f32x16;
typedef __attribute__((ext_vector_type(4))) unsigned int u32x4;
typedef unsigned short u16;
typedef unsigned int   u32;

// softmax scale folded into exp2: SCALE * log2(e)
#define KSC (0.08838834764831845f * 1.4426950408889634f)

__device__ __forceinline__ float bf2f(u16 v){ u32 u = ((u32)v) << 16; return __builtin_bit_cast(float, u); }
__device__ __forceinline__ u16 f2bf(float f){
  u32 u = __builtin_bit_cast(u32, f);
  u32 r = u + 0x7fffu + ((u >> 16) & 1u);   // RNE
  return (u16)(r >> 16);
}

__device__ __forceinline__ void gload_lds16(const void* g, void* lds){
  __builtin_amdgcn_global_load_lds(
      (const __attribute__((address_space(1))) void*)g,
      (__attribute__((address_space(3))) void*)lds, 16, 0, 0);
}

// ---------------- cast fp32 -> bf16 (vectorized) ----------------
__global__ void cast_f32_bf16(const float* __restrict__ in, u16* __restrict__ out, int n){
  int i = (blockIdx.x * blockDim.x + threadIdx.x) * 4;
  if (i >= n) return;
  float4 v = *(const float4*)(in + i);
  ushort4 o;
  o.x = f2bf(v.x); o.y = f2bf(v.y); o.z = f2bf(v.z); o.w = f2bf(v.w);
  *(ushort4*)(out + i) = o;
}

// ---------------- transpose-cast: W[Kd][Nd] fp32 -> WT[Nd][Kd] bf16 ----------------
__global__ __launch_bounds__(256) void tcast(const float* __restrict__ W, u16* __restrict__ WT,
                                             int Kd, int Nd){
  __shared__ __align__(16) u16 t[64][65];     // t[n][k]
  int k0 = blockIdx.x * 64, n0 = blockIdx.y * 64;
  int lx = threadIdx.x & 15, ly = threadIdx.x >> 4;
  #pragma unroll
  for (int rr = 0; rr < 4; ++rr){
    int r = rr * 16 + ly;                     // k-row in tile
    float4 v = *(const float4*)(W + (size_t)(k0 + r) * Nd + n0 + lx * 4);
    t[lx*4+0][r] = f2bf(v.x);
    t[lx*4+1][r] = f2bf(v.y);
    t[lx*4+2][r] = f2bf(v.z);
    t[lx*4+3][r] = f2bf(v.w);
  }
  __syncthreads();
  #pragma unroll
  for (int rr = 0; rr < 4; ++rr){
    int r = rr * 16 + ly;                     // n-row in tile
    ushort4 o;
    o.x = t[r][lx*4+0]; o.y = t[r][lx*4+1]; o.z = t[r][lx*4+2]; o.w = t[r][lx*4+3];
    *(ushort4*)(WT + (size_t)(n0 + r) * Kd + k0 + lx * 4) = o;
  }
}

// ---------------- transpose V (bf16): QKV[t][5120 + vd] -> Vt[b*1024+vd][s] ----------------
__global__ __launch_bounds__(256) void vtrans(const u16* __restrict__ QKV, u16* __restrict__ Vt){
  __shared__ __align__(16) u16 t[64][65];
  int stile = blockIdx.x;                 // 0..31
  int b = blockIdx.y >> 4, vt = blockIdx.y & 15;
  int s0 = stile * 64, c0 = vt * 64;
  int lx = threadIdx.x & 15, ly = threadIdx.x >> 4;
  #pragma unroll
  for (int rr = 0; rr < 4; ++rr){
    int r = rr * 16 + ly;                 // s-row
    ushort4 v = *(const ushort4*)(QKV + (size_t)(b*S_ + s0 + r) * QSTR + 5120 + c0 + lx*4);
    t[lx*4+0][r]=v.x; t[lx*4+1][r]=v.y; t[lx*4+2][r]=v.z; t[lx*4+3][r]=v.w;
  }
  __syncthreads();
  #pragma unroll
  for (int rr = 0; rr < 4; ++rr){
    int r = rr * 16 + ly;                 // vd-row
    ushort4 o;
    o.x=t[r][lx*4+0]; o.y=t[r][lx*4+1]; o.z=t[r][lx*4+2]; o.w=t[r][lx*4+3];
    *(ushort4*)(Vt + (size_t)(b*1024 + c0 + r) * S_ + s0 + lx*4) = o;
  }
}

// ---------------- RoPE in-place on bf16 [M_][stride] rows ----------------
__global__ void rope_k(u16* __restrict__ X, const int* __restrict__ pos, int hshift, int stride){
  int idx = blockIdx.x * 256 + threadIdx.x;
  int i = idx & 63;
  int h = (idx >> 6) & ((1 << hshift) - 1);
  int t = idx >> (6 + hshift);
  u16* p0 = X + (size_t)t * stride + h * D_ + i;
  float x1 = bf2f(p0[0]), x2 = bf2f(p0[64]);
  float fpos = (float)pos[t];
  float invf = exp2f(-(float)(2 * i) * (13.287712379549449f / 128.0f));
  float f = fpos * invf;
  float sv = __sinf(f), cv = __cosf(f);
  p0[0]  = f2bf(x1 * cv - x2 * sv);
  p0[64] = f2bf(x2 * cv + x1 * sv);
}

// ============ 256x256 8-phase GEMM (K=4096): C[M,N] = A[M,4096] @ Bt[N,4096]^T ============
// 8 waves (2Mx4N), BK=64, 128KB LDS dbuf, chunk-XOR swizzle, one-phase-ahead fragment reads,
// staging at ph2/ph3/ph4 into dead halves, vmcnt(6) hoist-fence at ph3.
// RAW barriers only — no sched_barrier (m141: order-pinning defeats compiler scheduling).
// Residency audit: every staged half is forced complete by a "memory"-clobber vmcnt asm
// >=1 phase before its ds_read; reads cannot hoist above those asms; WAR targets are
// >=2 barriers dead; register deps pin the ph4 refill after its consuming MFMA.

#define BAR() __builtin_amdgcn_s_barrier()

#define STG_A(PB, HALF, KT) do{ \
  gload_lds16(Ag + off0 + (size_t)(HALF)*1048576 + (size_t)(KT)*128, \
              (char*)smem + (PB)*32768 + (HALF)*16384 + w*1024); \
  gload_lds16(Ag + off0 + 524288 + (size_t)(HALF)*1048576 + (size_t)(KT)*128, \
              (char*)smem + (PB)*32768 + (HALF)*16384 + 8192 + w*1024); }while(0)
#define STG_B(PB, HALF, KT) do{ \
  gload_lds16(Bg + off0 + (size_t)(HALF)*1048576 + (size_t)(KT)*128, \
              (char*)smem + 65536 + (PB)*32768 + (HALF)*16384 + w*1024); \
  gload_lds16(Bg + off0 + 524288 + (size_t)(HALF)*1048576 + (size_t)(KT)*128, \
              (char*)smem + 65536 + (PB)*32768 + (HALF)*16384 + 8192 + w*1024); }while(0)

#define RD_A(DST, PP, HALF) do{ \
  _Pragma("unroll") for (int ks = 0; ks < 2; ++ks) \
  _Pragma("unroll") for (int m = 0; m < 4; ++m) \
    DST[ks][m] = *(const bf16x8*)&smem[(PP)*16384 + (HALF)*8192 + aRowBase + m*1024 + csw[ks]]; }while(0)
#define RD_B(DST, PP, HALF) do{ \
  _Pragma("unroll") for (int ks = 0; ks < 2; ++ks) \
  _Pragma("unroll") for (int n = 0; n < 2; ++n) \
    DST[ks][n] = *(const bf16x8*)&smem[32768 + (PP)*16384 + (HALF)*8192 + bRowBase + n*1024 + csw[ks]]; }while(0)

template<int MO, int NO>
__device__ __forceinline__ void mfma_quad(f32x4 (&acc)[8][4],
                                          const bf16x8 (&af)[2][4], const bf16x8 (&bf)[2][2]){
  __builtin_amdgcn_s_setprio(1);
  #pragma unroll
  for (int ks = 0; ks < 2; ++ks)
    #pragma unroll
    for (int m = 0; m < 4; ++m)
      #pragma unroll
      for (int n = 0; n < 2; ++n)
        acc[MO+m][NO+n] = __builtin_amdgcn_mfma_f32_16x16x32_bf16(af[ks][m], bf[ks][n], acc[MO+m][NO+n], 0, 0, 0);
  __builtin_amdgcn_s_setprio(0);
}

template<bool OUTF32>
__global__ __launch_bounds__(512, 2) void gemm256(const u16* __restrict__ A, const u16* __restrict__ Bt,
                                                  void* __restrict__ C, int Nn, int mt){
  __shared__ __align__(16) u16 smem[65536];   // 128 KB: As[2] bytes [0,65536), Bs[2] [65536,131072)
  const int tid = threadIdx.x;
  const int l = tid & 63, w = tid >> 6;
  const int lr = l & 15, lk = l >> 4;
  const int wr = w >> 2, wc = w & 3;

  // bijective XCD swizzle (nwg % 8 == 0 for both grids)
  const int nwg = gridDim.x;
  const int sbid = ((int)blockIdx.x & 7) * (nwg >> 3) + ((int)blockIdx.x >> 3);
  const int bx = sbid % mt, by = sbid / mt;
  const size_t arow0 = (size_t)bx * 256;
  const size_t brow0 = (size_t)by * 256;
  const char* Ag = (const char*)(A + arow0 * 4096);
  const char* Bg = (const char*)(Bt + brow0 * 4096);

  // per-thread staging source offset (row = w*8 + l/8, chunk = (l&7) ^ (row&7))
  const size_t off0 = (size_t)(w * 8 + (l >> 3)) * 8192 + (size_t)(((l & 7) ^ (l >> 3)) << 4);

  // ds_read bases (u16 units)
  const int aRowBase = (wr*64 + lr) * 64;
  const int bRowBase = (wc*32 + lr) * 64;
  int csw[2];
  csw[0] = ((lk     ) ^ (lr & 7)) << 3;
  csw[1] = ((lk + 4) ^ (lr & 7)) << 3;

  f32x4 acc[8][4];
  #pragma unroll
  for (int i = 0; i < 8; ++i)
    #pragma unroll
    for (int j = 0; j < 4; ++j){ acc[i][j][0]=0.f; acc[i][j][1]=0.f; acc[i][j][2]=0.f; acc[i][j][3]=0.f; }

  // prologue: stage tiles 0 and 1 completely (16 loads/wave), drain tile 0, preload A0/B0 frags
  STG_A(0, 0, 0); STG_B(0, 0, 0); STG_A(0, 1, 0); STG_B(0, 1, 0);
  STG_A(1, 0, 1); STG_B(1, 0, 1); STG_A(1, 1, 1); STG_B(1, 1, 1);
  asm volatile("s_waitcnt vmcnt(8)" ::: "memory");
  BAR();
  bf16x8 a0c[2][4], b0c[2][2], a1f[2][4], b1f[2][2];
  RD_A(a0c, 0, 0); RD_B(b0c, 0, 0);

  for (int t = 0; t < 64; ++t){
    const int P = t & 1;
    // ---- ph1: read A1[t] (used ph2); MFMA m0n0 on held A0/B0 ----
    RD_A(a1f, P, 1);
    BAR();
    mfma_quad<0,0>(acc, a0c, b0c);
    BAR();
    // ---- ph2: stage A0,B0[t+2] (halves freed end of t-1); read B1[t] (used ph3); MFMA m1n0 ----
    if (t < 62){ STG_A(P, 0, t+2); STG_B(P, 0, t+2); }
    RD_B(b1f, P, 1);
    BAR();
    mfma_quad<4,0>(acc, a1f, b0c);
    BAR();
    // ---- ph3: stage A1[t+2]; vmcnt(6) forces tile t+1 resident; MFMA m1n1 ----
    if (t < 62){
      STG_A(P, 1, t+2);
      asm volatile("s_waitcnt vmcnt(6)" ::: "memory");
    } else if (t == 62){
      asm volatile("s_waitcnt vmcnt(0)" ::: "memory");
    }
    BAR();
    mfma_quad<4,2>(acc, a1f, b1f);
    BAR();
    // ---- ph4: stage B1[t+2]; MFMA m0n1; refill A0/B0 regs from tile t+1 (reg deps pin order) ----
    if (t < 62){ STG_B(P, 1, t+2); }
    BAR();
    mfma_quad<0,2>(acc, a0c, b1f);
    if (t < 63){ RD_A(a0c, P^1, 0); RD_B(b0c, P^1, 0); }
    BAR();
  }

  // epilogue: C row = ... + lk*4 + j, col = ... + lr  [m89 layout]
  #pragma unroll
  for (int mh = 0; mh < 2; ++mh)
    #pragma unroll
    for (int m = 0; m < 4; ++m)
      #pragma unroll
      for (int nh = 0; nh < 2; ++nh)
        #pragma unroll
        for (int n = 0; n < 2; ++n)
          #pragma unroll
          for (int j = 0; j < 4; ++j){
            size_t gr = arow0 + mh*128 + wr*64 + m*16 + lk*4 + j;
            size_t gc = brow0 + nh*128 + wc*32 + n*16 + lr;
            float v = acc[mh*4+m][nh*2+n][j];
            if (OUTF32) ((float*)C)[gr * Nn + gc] = v;
            else        ((u16*)C)[gr * Nn + gc] = f2bf(v);
          }
}

// ---------------- flash attention: 8 waves x 32 q-rows, KVBLK=64, 32x32x16 MFMA ----------------
__global__ __launch_bounds__(512, 2) void attn_k(const u16* __restrict__ QKV,
                                                 const u16* __restrict__ Vtg,
                                                 u16* __restrict__ ctx){
  __shared__ __align__(16) u16 smem[32768];   // 64 KB
  const int tid = threadIdx.x;
  const int l = tid & 63, w = tid >> 6;
  const int lane31 = l & 31, hi = l >> 5;
  const int hb = blockIdx.x;
  const int b = hb >> 5, h = hb & 31, kvh = h >> 2;
  const int qb = 7 - blockIdx.y;              // LPT
  const int q0w = qb * 256 + w * 32;
  const int qg = q0w + lane31;

  const u16* Qp = QKV + (size_t)b * S_ * QSTR + (size_t)h * D_;
  const char* Kp = (const char*)(QKV + (size_t)b * S_ * QSTR + 4096 + (size_t)kvh * D_);
  const char* Vp = (const char*)(Vtg + ((size_t)b * 1024 + kvh * 128) * S_);

  bf16x8 qf[8];
  #pragma unroll
  for (int dt = 0; dt < 8; ++dt)
    qf[dt] = *(const bf16x8*)(Qp + (size_t)qg * QSTR + dt * 16 + hi * 8);

  const int krow0 = (2*w)*4 + (l >> 4), krow1 = krow0 + 4;
  const size_t koff0 = (size_t)krow0 * (QSTR*2) + (((l & 15) << 4) ^ ((krow0 & 7) << 4));
  const size_t koff1 = (size_t)krow1 * (QSTR*2) + (((l & 15) << 4) ^ ((krow1 & 7) << 4));
  const int vrow0 = (2*w)*8 + (l >> 3), vrow1 = vrow0 + 8;
  const size_t voff0 = (size_t)vrow0 * (S_*2) + (((l & 7) << 4) ^ ((vrow0 & 7) << 4));
  const size_t voff1 = (size_t)vrow1 * (S_*2) + (((l & 7) << 4) ^ ((vrow1 & 7) << 4));

  f32x16 acc[4];
  #pragma unroll
  for (int dt = 0; dt < 4; ++dt)
    #pragma unroll
    for (int i = 0; i < 16; ++i) acc[dt][i] = 0.f;
  float mrow = -3e38f, lsum = 0.f;

  const int nt = qb * 4 + 4;

  auto STAGE = [&](int t, int bufn){
    char* Kb = (char*)smem + bufn * 16384;
    char* Vb = (char*)smem + 32768 + bufn * 16384;
    size_t kb = (size_t)t * 64 * (QSTR*2);
    size_t vb = (size_t)t * 128;
    gload_lds16(Kp + kb + koff0, Kb + (2*w)*1024);
    gload_lds16(Kp + kb + koff1, Kb + (2*w+1)*1024);
    gload_lds16(Vp + vb + voff0, Vb + (2*w)*1024);
    gload_lds16(Vp + vb + voff1, Vb + (2*w+1)*1024);
  };

  STAGE(0, 0);
  __syncthreads();
  int buf = 0;
  for (int t = 0; t < nt; ++t){
    if (t + 1 < nt) STAGE(t + 1, buf ^ 1);
    const int kbase = t * 64;
    if (kbase <= q0w + 31){
      const char* Kb = (const char*)smem + buf * 16384;
      const char* Vb = (const char*)smem + 32768 + buf * 16384;
      const int swz = (lane31 & 7) << 4;

      f32x16 s0, s1;
      #pragma unroll
      for (int i = 0; i < 16; ++i){ s0[i] = 0.f; s1[i] = 0.f; }
      #pragma unroll
      for (int dt = 0; dt < 8; ++dt){
        bf16x8 kf = *(const bf16x8*)(Kb + lane31*256 + ((dt*32 + hi*16) ^ swz));
        s0 = __builtin_amdgcn_mfma_f32_32x32x16_bf16(kf, qf[dt], s0, 0, 0, 0);
      }
      #pragma unroll
      for (int dt = 0; dt < 8; ++dt){
        bf16x8 kf = *(const bf16x8*)(Kb + (32 + lane31)*256 + ((dt*32 + hi*16) ^ swz));
        s1 = __builtin_amdgcn_mfma_f32_32x32x16_bf16(kf, qf[dt], s1, 0, 0, 0);
      }

      if (kbase + 63 > q0w){
        int thr = qg - kbase;
        #pragma unroll
        for (int r = 0; r < 16; ++r){
          int kc = (r & 3) + 8*(r >> 2) + 4*hi;
          s0[r] = (kc > thr)      ? -1e30f : s0[r];
          s1[r] = (kc + 32 > thr) ? -1e30f : s1[r];
        }
      }

      float tmax = s0[0];
      #pragma unroll
      for (int r = 1; r < 16; ++r) tmax = fmaxf(tmax, s0[r]);
      #pragma unroll
      for (int r = 0; r < 16; ++r) tmax = fmaxf(tmax, s1[r]);
      tmax = fmaxf(tmax, __shfl_xor(tmax, 32));
      float mn = fmaxf(mrow, tmax);
      float rf = exp2f((mrow - mn) * KSC);
      mrow = mn;
      float ps = 0.f;
      #pragma unroll
      for (int r = 0; r < 16; ++r){
        float a = exp2f((s0[r] - mn) * KSC);
        float c = exp2f((s1[r] - mn) * KSC);
        s0[r] = a; s1[r] = c; ps += a + c;
      }
      ps += __shfl_xor(ps, 32);
      lsum = lsum * rf + ps;
      #pragma unroll
      for (int dt = 0; dt < 4; ++dt)
        #pragma unroll
        for (int i = 0; i < 16; ++i) acc[dt][i] *= rf;

      u32 pw[16];
      #pragma unroll
      for (int g = 0; g < 4; ++g){
        pw[2*g]     = (u32)f2bf(s0[4*g])   | ((u32)f2bf(s0[4*g+1]) << 16);
        pw[2*g+1]   = (u32)f2bf(s0[4*g+2]) | ((u32)f2bf(s0[4*g+3]) << 16);
        pw[8+2*g]   = (u32)f2bf(s1[4*g])   | ((u32)f2bf(s1[4*g+1]) << 16);
        pw[8+2*g+1] = (u32)f2bf(s1[4*g+2]) | ((u32)f2bf(s1[4*g+3]) << 16);
      }

      #pragma unroll
      for (int kt = 0; kt < 4; ++kt){
        u32 W0 = pw[kt*4+0], W1 = pw[kt*4+1], W2 = pw[kt*4+2], W3 = pw[kt*4+3];
        u32 x0 = hi ? W0 : W2;
        u32 x1 = hi ? W1 : W3;
        u32 y0 = __shfl_xor(x0, 32);
        u32 y1 = __shfl_xor(x1, 32);
        u32 w0 = hi ? y0 : W0;
        u32 w1 = hi ? y1 : W1;
        u32 w2 = hi ? W2 : y0;
        u32 w3 = hi ? W3 : y1;
        u32x4 pk; pk[0]=w0; pk[1]=w1; pk[2]=w2; pk[3]=w3;
        bf16x8 pa = __builtin_bit_cast(bf16x8, pk);
        #pragma unroll
        for (int dt = 0; dt < 4; ++dt){
          bf16x8 vf = *(const bf16x8*)(Vb + (dt*32 + lane31)*128 + ((kt*32 + hi*16) ^ swz));
          acc[dt] = __builtin_amdgcn_mfma_f32_32x32x16_bf16(vf, pa, acc[dt], 0, 0, 0);
        }
      }
    }
    __syncthreads();
    buf ^= 1;
  }

  __syncthreads();
  u16* Ot = smem + w * 4096;
  float inv = 1.f / lsum;
  #pragma unroll
  for (int dt = 0; dt < 4; ++dt)
    #pragma unroll
    for (int r = 0; r < 16; ++r){
      int d = dt*32 + (r & 3) + 8*(r >> 2) + 4*hi;
      Ot[lane31*128 + (d ^ ((lane31 & 15) << 2))] = f2bf(acc[dt][r] * inv);
    }
  u16* outp = ctx + ((size_t)(b * S_ + q0w)) * HID_ + h * D_;
  #pragma unroll
  for (int it = 0; it < 16; ++it){
    int id = it * 64 + l;
    int q = id >> 5;
    int c4 = (id & 31) * 4;
    ushort4 vv = *(const ushort4*)(Ot + q*128 + (c4 ^ ((q & 15) << 2)));
    *(ushort4*)(outp + (size_t)q * HID_ + c4) = vv;
  }
}

extern "C" void kernel_launch(void* const* d_in, const int* in_sizes, int n_in,
                              void* d_out, int out_size, void* d_ws, size_t ws_size,
                              hipStream_t stream) {
  const float* x  = (const float*)d_in[0];
  const int*   pos = (const int*)d_in[2];
  const float* Wq = (const float*)d_in[3];
  const float* Wk = (const float*)d_in[4];
  const float* Wv = (const float*)d_in[5];
  const float* Wo = (const float*)d_in[6];

  char* ws = (char*)d_ws;
  u16* xb   = (u16*)(ws);                               // 32MB; reused as ctx after QKV
  u16* WT   = (u16*)(ws + ((size_t)32 << 20));          // 48MB: Wq^T|Wk^T|Wv^T (dead after QKV gemm)
  u16* WoT  = (u16*)(ws + ((size_t)80 << 20));          // 32MB
  u16* QKVb = (u16*)(ws + ((size_t)112 << 20));         // 48MB: [4096][6144]
  u16* Vtg  = (u16*)(ws + ((size_t)32 << 20));          // 8MB overlay on WT: [b*1024+vd][S]

  cast_f32_bf16<<<16384, 256, 0, stream>>>(x, xb, HID_ * M_);
  tcast<<<dim3(64, 64), 256, 0, stream>>>(Wq, WT, 4096, 4096);
  tcast<<<dim3(64, 16), 256, 0, stream>>>(Wk, WT + (size_t)4096 * 4096, 4096, 1024);
  tcast<<<dim3(64, 16), 256, 0, stream>>>(Wv, WT + (size_t)5120 * 4096, 4096, 1024);
  tcast<<<dim3(64, 64), 256, 0, stream>>>(Wo, WoT, 4096, 4096);
  gemm256<false><<<16 * 24, 512, 0, stream>>>(xb, WT, QKVb, 6144, 16);
  rope_k<<<32768, 256, 0, stream>>>(QKVb,        pos, 5, QSTR);
  rope_k<<<8192,  256, 0, stream>>>(QKVb + 4096, pos, 3, QSTR);
  vtrans<<<dim3(32, 32), 256, 0, stream>>>(QKVb, Vtg);
  attn_k<<<dim3(64, 8), 512, 0, stream>>>(QKVb, Vtg, xb);
  gemm256<true><<<16 * 16, 512, 0, stream>>>(xb, WoT, d_out, 4096, 16);
}